// Round 6
// baseline (197.022 us; speedup 1.0000x reference)
//
#include <hip/hip_runtime.h>
#include <math.h>

#define Bc 8
#define Nseq 512
#define DM 512
#define Hh 8
#define NUMREL 1023
#define ZOFF 511   // NUMREL/2
#define PVROWS 1040  // Pvt padded g-extent (>= 496+544, mult of 16)

typedef short bf16x8 __attribute__((ext_vector_type(8)));
typedef float f32x4 __attribute__((ext_vector_type(4)));

__device__ __forceinline__ unsigned short f2bf(float f) {
  unsigned u = __builtin_bit_cast(unsigned, f);
  u += 0x7fff + ((u >> 16) & 1);   // RNE
  return (unsigned short)(u >> 16);
}
__device__ __forceinline__ float bf2f(unsigned short h) {
  unsigned u = ((unsigned)h) << 16;
  return __builtin_bit_cast(float, u);
}

// ---------------------------------------------------------------------------
// prep_cvt: X fp32 -> bf16 (2M elems), float4 vectorized.
// ---------------------------------------------------------------------------
__global__ __launch_bounds__(256) void prep_cvt(const float* __restrict__ X,
                                                unsigned short* __restrict__ Xb) {
  int idx = blockIdx.x * 256 + threadIdx.x;
  float4 v = ((const float4*)X)[idx];
  ushort4 o;
  o.x = f2bf(v.x); o.y = f2bf(v.y); o.z = f2bf(v.z); o.w = f2bf(v.w);
  ((ushort4*)Xb)[idx] = o;
}

// ---------------------------------------------------------------------------
// pv_trans: Pv [1023][8][64] fp32 -> Pvt [8*64][PVROWS] bf16 (g-contiguous,
// zero-padded rows g in [1023, PVROWS)). grid (17, 8).
// ---------------------------------------------------------------------------
__global__ __launch_bounds__(256) void pv_trans(const float* __restrict__ Pv,
                                                unsigned short* __restrict__ Pvt) {
  const int g0 = blockIdx.x * 64, hd0 = blockIdx.y * 64;
  __shared__ float t[64][65];
  const int tid = threadIdx.x;
#pragma unroll
  for (int u = 0; u < 16; ++u) {
    int idx = u * 256 + tid, r = idx >> 6, c = idx & 63;
    int g = g0 + r;
    t[r][c] = g < NUMREL ? Pv[(size_t)g * 512 + hd0 + c] : 0.f;
  }
  __syncthreads();
#pragma unroll
  for (int u = 0; u < 16; ++u) {
    int idx = u * 256 + tid, r = idx >> 6, c = idx & 63;
    int g = g0 + c;
    if (g < PVROWS) Pvt[(size_t)(hd0 + r) * PVROWS + g] = f2bf(t[c][r]);
  }
}

// ---------------------------------------------------------------------------
// wtrans: W[K,N] -> Wt[n][k] bf16. z=0..2: Wq/Wk/Wv; z=3: Wo hi; z=4: Wo lo.
// ---------------------------------------------------------------------------
__global__ __launch_bounds__(256) void wtrans(const float* __restrict__ Wq,
                                              const float* __restrict__ Wk,
                                              const float* __restrict__ Wv,
                                              const float* __restrict__ Wo,
                                              unsigned short* __restrict__ Wqt,
                                              unsigned short* __restrict__ Wkt,
                                              unsigned short* __restrict__ Wvt,
                                              unsigned short* __restrict__ Woth,
                                              unsigned short* __restrict__ Wotl) {
  const int z = blockIdx.z;
  const float* src = z == 0 ? Wq : z == 1 ? Wk : z == 2 ? Wv : Wo;
  unsigned short* dst = z == 0 ? Wqt : z == 1 ? Wkt : z == 2 ? Wvt : z == 3 ? Woth : Wotl;
  const int k0 = blockIdx.y * 32, n0 = blockIdx.x * 32;
  __shared__ float t[32][33];
  const int tid = threadIdx.x;
#pragma unroll
  for (int u = 0; u < 4; ++u) {
    int idx = u * 256 + tid, r = idx >> 5, c = idx & 31;
    t[r][c] = src[(size_t)(k0 + r) * DM + n0 + c];
  }
  __syncthreads();
#pragma unroll
  for (int u = 0; u < 4; ++u) {
    int idx = u * 256 + tid, r = idx >> 5, c = idx & 31;
    float v = t[c][r];
    unsigned short hv = f2bf(v);
    if (z == 4) hv = f2bf(v - bf2f(hv));
    dst[(size_t)(n0 + r) * DM + k0 + c] = hv;
  }
}

// ---------------------------------------------------------------------------
// gemm_qkv: z-FUSED bf16 MFMA, no LDS. One block computes the 64x64 tile of
// Q, K and V (A-fragments reused in registers, 12 MFMA per K-step per wave).
// Explicit ping-pong software pipeline over the fully-unrolled K-loop.
// Outputs: Qb/Kb [(bh)*N+i][64]; Vt [(bh)*64+d][512] (transposed). grid (8,64).
// ---------------------------------------------------------------------------
__global__ __launch_bounds__(256) void gemm_qkv(const unsigned short* __restrict__ Xb,
                                                const unsigned short* __restrict__ Wqt,
                                                const unsigned short* __restrict__ Wkt,
                                                const unsigned short* __restrict__ Wvt,
                                                const float* __restrict__ bq,
                                                const float* __restrict__ bk,
                                                const float* __restrict__ bv,
                                                unsigned short* __restrict__ Qb,
                                                unsigned short* __restrict__ Kb,
                                                unsigned short* __restrict__ Vt) {
  const int bm = blockIdx.y * 64, bn = blockIdx.x * 64;
  const int tid = threadIdx.x, w = tid >> 6, lane = tid & 63;
  const int lo = lane & 15, quad = lane >> 4;
  const int mt = (w >> 1) * 32, nt = (w & 1) * 32;

  const unsigned short* arow0 = Xb + (size_t)(bm + mt + lo) * DM + quad * 8;
  const unsigned short* arow1 = arow0 + 16 * DM;
  const size_t ncol0 = (size_t)(bn + nt + lo) * DM + quad * 8;
  const size_t ncol1 = ncol0 + 16 * DM;

  f32x4 acc[3][2][2] = {};
  bf16x8 af[2][2], bfq[2][2], bfk[2][2], bfv[2][2];

#define LOADK(buf, k0)                                                      \
  do {                                                                      \
    af[buf][0] = *(const bf16x8*)(arow0 + (k0));                            \
    af[buf][1] = *(const bf16x8*)(arow1 + (k0));                            \
    bfq[buf][0] = *(const bf16x8*)(Wqt + ncol0 + (k0));                     \
    bfq[buf][1] = *(const bf16x8*)(Wqt + ncol1 + (k0));                     \
    bfk[buf][0] = *(const bf16x8*)(Wkt + ncol0 + (k0));                     \
    bfk[buf][1] = *(const bf16x8*)(Wkt + ncol1 + (k0));                     \
    bfv[buf][0] = *(const bf16x8*)(Wvt + ncol0 + (k0));                     \
    bfv[buf][1] = *(const bf16x8*)(Wvt + ncol1 + (k0));                     \
  } while (0)

  LOADK(0, 0);
#pragma unroll
  for (int ks = 0; ks < 16; ++ks) {
    const int cur = ks & 1, nxt = cur ^ 1;
    if (ks < 15) LOADK(nxt, (ks + 1) * 32);
#pragma unroll
    for (int i = 0; i < 2; ++i)
#pragma unroll
      for (int j = 0; j < 2; ++j) {
        acc[0][i][j] = __builtin_amdgcn_mfma_f32_16x16x32_bf16(af[cur][i], bfq[cur][j], acc[0][i][j], 0, 0, 0);
        acc[1][i][j] = __builtin_amdgcn_mfma_f32_16x16x32_bf16(af[cur][i], bfk[cur][j], acc[1][i][j], 0, 0, 0);
        acc[2][i][j] = __builtin_amdgcn_mfma_f32_16x16x32_bf16(af[cur][i], bfv[cur][j], acc[2][i][j], 0, 0, 0);
      }
  }
#undef LOADK

#pragma unroll
  for (int z = 0; z < 3; ++z) {
    const float* bias = z == 0 ? bq : z == 1 ? bk : bv;
#pragma unroll
    for (int i = 0; i < 2; ++i)
#pragma unroll
      for (int j = 0; j < 2; ++j) {
        int col = bn + nt + j * 16 + lo;
        int h = col >> 6, d = col & 63;
        float bv_ = bias[col];
#pragma unroll
        for (int r = 0; r < 4; ++r) {
          int row = bm + mt + i * 16 + quad * 4 + r;
          int b = row >> 9, is = row & 511;
          unsigned short val = f2bf(acc[z][i][j][r] + bv_);
          if (z == 2)
            Vt[((size_t)(b * Hh + h) * 64 + d) * 512 + is] = val;
          else if (z == 0)
            Qb[((size_t)(b * Hh + h) * Nseq + is) * 64 + d] = val;
          else
            Kb[((size_t)(b * Hh + h) * Nseq + is) * 64 + d] = val;
        }
      }
  }
}

// ---------------------------------------------------------------------------
// attn_fused: per block = (b, h, 16-row i-tile). 1-D grid with XCD swizzle:
// flat%8 pins (b,h)%8 so all 32 i-tiles of one (b,h) share an XCD L2.
// Phase 1: QK^T + Pk softmax with ALL 16 K-fragments preloaded to registers.
// Phase 2: P@V + P'@Pv with V/Pv B-fragments batch-preloaded from global.
// ---------------------------------------------------------------------------
#define PSV 520  // pstrip row stride (elems): 4*odd -> 2-way aliasing (free)
#define PSH 552  // pshift row stride (elems): 4*odd -> 2-way aliasing (free)

__global__ __launch_bounds__(256) void attn_fused(const unsigned short* __restrict__ Qb,
                                                  const unsigned short* __restrict__ Kb,
                                                  const unsigned short* __restrict__ Vt,
                                                  const float* __restrict__ Pk,
                                                  const unsigned short* __restrict__ Pvt,
                                                  unsigned short* __restrict__ Awh,
                                                  unsigned short* __restrict__ Awl) {
  // XCD-aware decode: bh64 % 8 == flat % 8
  const int flat = blockIdx.x;
  const int xcd = flat & 7;
  const int grp = flat >> 3;
  const int i0 = (grp & 31) * 16;
  const int bh = (grp >> 5) * 8 + xcd;   // b*8+h
  const int b = bh >> 3, h = bh & 7;
  const int tid = threadIdx.x;
  const int w = tid >> 6;
  const int lane = tid & 63;
  const int lo = lane & 15, quad = lane >> 4;

  __shared__ __align__(16) unsigned short pstrip[16 * PSV];
  __shared__ __align__(16) unsigned short pshift[16 * PSH];
  __shared__ float pk_lds[544];
  __shared__ float redm[4][16];
  __shared__ float redl[4][16];

  // zero pshift (pads beyond the diagonal band must be 0); pstrip fully written
  int4 z4; z4.x = z4.y = z4.z = z4.w = 0;
  for (int c = tid; c < 16 * PSH / 8; c += 256) ((int4*)pshift)[c] = z4;
  for (int t = tid; t < 527; t += 256)
    pk_lds[t] = Pk[(size_t)(ZOFF - i0 - 15 + t) * Hh + h];

  // ---------------- Phase 1: scores + softmax ----------------
  const unsigned short* qbase = Qb + ((size_t)bh * Nseq + i0 + lo) * 64;
  bf16x8 qa0 = *(const bf16x8*)(qbase + quad * 8);
  bf16x8 qa1 = *(const bf16x8*)(qbase + 32 + quad * 8);

  const int jw = w * 128;
  // preload ALL K B-fragments for this wave's 128-col strip (16 loads in flight)
  bf16x8 kb0[8], kb1[8];
#pragma unroll
  for (int s = 0; s < 8; ++s) {
    const unsigned short* kbase = Kb + ((size_t)bh * Nseq + jw + s * 16 + lo) * 64;
    kb0[s] = *(const bf16x8*)(kbase + quad * 8);
    kb1[s] = *(const bf16x8*)(kbase + 32 + quad * 8);
  }
  __syncthreads();  // pk_lds/pshift-zero ready

  float sv[8][4];
  float mrow[4] = {-1e30f, -1e30f, -1e30f, -1e30f};
#pragma unroll
  for (int s = 0; s < 8; ++s) {
    f32x4 c = {0.f, 0.f, 0.f, 0.f};
    c = __builtin_amdgcn_mfma_f32_16x16x32_bf16(qa0, kb0[s], c, 0, 0, 0);
    c = __builtin_amdgcn_mfma_f32_16x16x32_bf16(qa1, kb1[s], c, 0, 0, 0);
    int j = jw + s * 16 + lo;
#pragma unroll
    for (int r = 0; r < 4; ++r) {
      int rl = quad * 4 + r;
      float v = (c[r] + pk_lds[j - rl + 15]) * 0.125f;
      sv[s][r] = v;
      mrow[r] = fmaxf(mrow[r], v);
    }
  }
#pragma unroll
  for (int m = 1; m <= 8; m <<= 1)
#pragma unroll
    for (int r = 0; r < 4; ++r) mrow[r] = fmaxf(mrow[r], __shfl_xor(mrow[r], m));
  if (lo == 0)
#pragma unroll
    for (int r = 0; r < 4; ++r) redm[w][quad * 4 + r] = mrow[r];
  __syncthreads();
  float mfin[4];
#pragma unroll
  for (int r = 0; r < 4; ++r) {
    int rl = quad * 4 + r;
    mfin[r] = fmaxf(fmaxf(redm[0][rl], redm[1][rl]), fmaxf(redm[2][rl], redm[3][rl]));
  }
  float lrow[4] = {0.f, 0.f, 0.f, 0.f};
#pragma unroll
  for (int s = 0; s < 8; ++s)
#pragma unroll
    for (int r = 0; r < 4; ++r) {
      float e = __expf(sv[s][r] - mfin[r]);
      sv[s][r] = e;
      lrow[r] += e;
    }
#pragma unroll
  for (int m = 1; m <= 8; m <<= 1)
#pragma unroll
    for (int r = 0; r < 4; ++r) lrow[r] += __shfl_xor(lrow[r], m);
  if (lo == 0)
#pragma unroll
    for (int r = 0; r < 4; ++r) redl[w][quad * 4 + r] = lrow[r];
  __syncthreads();
#pragma unroll
  for (int r = 0; r < 4; ++r) {
    int rl = quad * 4 + r;
    float linv = 1.f / (redl[0][rl] + redl[1][rl] + redl[2][rl] + redl[3][rl]);
#pragma unroll
    for (int s = 0; s < 8; ++s) {
      int j = jw + s * 16 + lo;
      unsigned short pb = f2bf(sv[s][r] * linv);
      pstrip[rl * PSV + j] = pb;
      pshift[rl * PSH + j - rl + 15] = pb;
    }
  }
  __syncthreads();

  // ---------------- Phase 2: P@V + P'@Pv (no barriers) ----------------
  f32x4 oacc = {0.f, 0.f, 0.f, 0.f};
  const int d = w * 16 + lo;

  // V GEMM: preload all 16 B-fragments, then MFMA chain
  const unsigned short* vrow = Vt + ((size_t)bh * 64 + d) * 512;
  bf16x8 vbf[16];
#pragma unroll
  for (int ks = 0; ks < 16; ++ks)
    vbf[ks] = *(const bf16x8*)(vrow + ks * 32 + quad * 8);
#pragma unroll
  for (int ks = 0; ks < 16; ++ks) {
    bf16x8 pa = *(const bf16x8*)(pstrip + lo * PSV + ks * 32 + quad * 8);
    oacc = __builtin_amdgcn_mfma_f32_16x16x32_bf16(pa, vbf[ks], oacc, 0, 0, 0);
  }

  // Pv shifted GEMM: preload all 17 B-fragments
  const int tminrow = ZOFF - i0 - 15;  // multiple of 16, >= 0
  const unsigned short* pvrow = Pvt + ((size_t)h * 64 + d) * PVROWS + tminrow;
  bf16x8 pvf[17];
#pragma unroll
  for (int ks = 0; ks < 17; ++ks)
    pvf[ks] = *(const bf16x8*)(pvrow + ks * 32 + quad * 8);
#pragma unroll
  for (int ks = 0; ks < 17; ++ks) {
    bf16x8 pa = *(const bf16x8*)(pshift + lo * PSH + ks * 32 + quad * 8);
    oacc = __builtin_amdgcn_mfma_f32_16x16x32_bf16(pa, pvf[ks], oacc, 0, 0, 0);
  }

  // write Aw hi/lo bf16, layout [b*N+i][H*64]
#pragma unroll
  for (int r = 0; r < 4; ++r) {
    int i = i0 + quad * 4 + r;
    float o = oacc[r];
    unsigned short hi = f2bf(o);
    unsigned short lov = f2bf(o - bf2f(hi));
    size_t off = ((size_t)(b * Nseq + i)) * (Hh * 64) + h * 64 + d;
    Awh[off] = hi;
    Awl[off] = lov;
  }
}

// ---------------------------------------------------------------------------
// gemm_final: split-bf16 (3-term) MFMA GEMM. out = Ah@Bh + Ah@Bl + Al@Bh + bo
// ---------------------------------------------------------------------------
__global__ __launch_bounds__(256) void gemm_final(const unsigned short* __restrict__ Ah,
                                                  const unsigned short* __restrict__ Al,
                                                  const unsigned short* __restrict__ Bh,
                                                  const unsigned short* __restrict__ Bl,
                                                  const float* __restrict__ bo,
                                                  float* __restrict__ out) {
  const int bm = blockIdx.y * 64, bn = blockIdx.x * 64;
  const int tid = threadIdx.x, w = tid >> 6, lane = tid & 63;
  const int lo = lane & 15, quad = lane >> 4;
  const int mt = (w >> 1) * 32, nt = (w & 1) * 32;

  const size_t arow0 = (size_t)(bm + mt + lo) * DM + quad * 8;
  const size_t arow1 = arow0 + 16 * DM;
  const size_t ncol0 = (size_t)(bn + nt + lo) * DM + quad * 8;
  const size_t ncol1 = ncol0 + 16 * DM;

  f32x4 acc[2][2] = {};
  bf16x8 ah[2][2], al[2][2], bh[2][2], bl[2][2];

#define LOADK2(buf, k0)                                       \
  do {                                                        \
    ah[buf][0] = *(const bf16x8*)(Ah + arow0 + (k0));         \
    ah[buf][1] = *(const bf16x8*)(Ah + arow1 + (k0));         \
    al[buf][0] = *(const bf16x8*)(Al + arow0 + (k0));         \
    al[buf][1] = *(const bf16x8*)(Al + arow1 + (k0));         \
    bh[buf][0] = *(const bf16x8*)(Bh + ncol0 + (k0));         \
    bh[buf][1] = *(const bf16x8*)(Bh + ncol1 + (k0));         \
    bl[buf][0] = *(const bf16x8*)(Bl + ncol0 + (k0));         \
    bl[buf][1] = *(const bf16x8*)(Bl + ncol1 + (k0));         \
  } while (0)

  LOADK2(0, 0);
#pragma unroll
  for (int ks = 0; ks < 16; ++ks) {
    const int cur = ks & 1, nxt = cur ^ 1;
    if (ks < 15) LOADK2(nxt, (ks + 1) * 32);
#pragma unroll
    for (int i = 0; i < 2; ++i)
#pragma unroll
      for (int j = 0; j < 2; ++j) {
        acc[i][j] = __builtin_amdgcn_mfma_f32_16x16x32_bf16(ah[cur][i], bh[cur][j], acc[i][j], 0, 0, 0);
        acc[i][j] = __builtin_amdgcn_mfma_f32_16x16x32_bf16(ah[cur][i], bl[cur][j], acc[i][j], 0, 0, 0);
        acc[i][j] = __builtin_amdgcn_mfma_f32_16x16x32_bf16(al[cur][i], bh[cur][j], acc[i][j], 0, 0, 0);
      }
  }
#undef LOADK2

#pragma unroll
  for (int i = 0; i < 2; ++i)
#pragma unroll
    for (int j = 0; j < 2; ++j) {
      int col = bn + nt + j * 16 + lo;
      float bb = bo[col];
#pragma unroll
      for (int r = 0; r < 4; ++r) {
        int row = bm + mt + i * 16 + quad * 4 + r;
        out[(size_t)row * DM + col] = acc[i][j][r] + bb;
      }
    }
}

// ---------------------------------------------------------------------------
extern "C" void kernel_launch(void* const* d_in, const int* in_sizes, int n_in,
                              void* d_out, int out_size, void* d_ws, size_t ws_size,
                              hipStream_t stream) {
  const float* X  = (const float*)d_in[0];
  const float* Wq = (const float*)d_in[1];
  const float* bq = (const float*)d_in[2];
  const float* Wk = (const float*)d_in[3];
  const float* bk = (const float*)d_in[4];
  const float* Wv = (const float*)d_in[5];
  const float* bv = (const float*)d_in[6];
  const float* Wo = (const float*)d_in[7];
  const float* bo = (const float*)d_in[8];
  const float* Pk = (const float*)d_in[9];
  const float* Pv = (const float*)d_in[10];
  float* out = (float*)d_out;

  char* p = (char*)d_ws;
  const size_t szX   = (size_t)Bc * Nseq * DM * 2;          // 4 MB
  const size_t szW   = (size_t)DM * DM * 2;                 // 512 KB
  const size_t szPvt = (size_t)Hh * 64 * PVROWS * 2;        // ~1 MB
  const size_t szQKV = (size_t)Bc * Hh * Nseq * 64 * 2;     // 4 MB
  unsigned short* Xb   = (unsigned short*)p; p += szX;
  unsigned short* Wqt  = (unsigned short*)p; p += szW;
  unsigned short* Wkt  = (unsigned short*)p; p += szW;
  unsigned short* Wvt  = (unsigned short*)p; p += szW;
  unsigned short* Woth = (unsigned short*)p; p += szW;
  unsigned short* Wotl = (unsigned short*)p; p += szW;
  unsigned short* Pvt  = (unsigned short*)p; p += szPvt;
  unsigned short* Qb   = (unsigned short*)p; p += szQKV;
  unsigned short* Kb   = (unsigned short*)p; p += szQKV;
  unsigned short* Vt   = (unsigned short*)p; p += szQKV;
  unsigned short* Awh  = (unsigned short*)p; p += szX;
  unsigned short* Awl  = (unsigned short*)p; p += szX;

  dim3 blk(256);
  prep_cvt<<<dim3(2048), blk, 0, stream>>>(X, Xb);
  pv_trans<<<dim3(17, 8), blk, 0, stream>>>(Pv, Pvt);
  wtrans<<<dim3(16, 16, 5), blk, 0, stream>>>(Wq, Wk, Wv, Wo, Wqt, Wkt, Wvt, Woth, Wotl);
  gemm_qkv<<<dim3(8, 64), blk, 0, stream>>>(Xb, Wqt, Wkt, Wvt, bq, bk, bv, Qb, Kb, Vt);
  attn_fused<<<dim3(2048), blk, 0, stream>>>(Qb, Kb, Vt, Pk, Pvt, Awh, Awl);
  gemm_final<<<dim3(8, 64), blk, 0, stream>>>(Awh, Awl, Woth, Wotl, bo, out);
}

// Round 7
// 195.813 us; speedup vs baseline: 1.0062x; 1.0062x over previous
//
#include <hip/hip_runtime.h>
#include <math.h>

#define Bc 8
#define Nseq 512
#define DM 512
#define Hh 8
#define NUMREL 1023
#define ZOFF 511   // NUMREL/2
#define PVROWS 1040  // Pvt padded g-extent (>= 496+544, mult of 16)

typedef short bf16x8 __attribute__((ext_vector_type(8)));
typedef float f32x4 __attribute__((ext_vector_type(4)));

__device__ __forceinline__ unsigned short f2bf(float f) {
  unsigned u = __builtin_bit_cast(unsigned, f);
  u += 0x7fff + ((u >> 16) & 1);   // RNE
  return (unsigned short)(u >> 16);
}
__device__ __forceinline__ float bf2f(unsigned short h) {
  unsigned u = ((unsigned)h) << 16;
  return __builtin_bit_cast(float, u);
}

// ---------------------------------------------------------------------------
// prep_cvt: X fp32 -> bf16 (2M elems), float4 vectorized.
// ---------------------------------------------------------------------------
__global__ __launch_bounds__(256) void prep_cvt(const float* __restrict__ X,
                                                unsigned short* __restrict__ Xb) {
  int idx = blockIdx.x * 256 + threadIdx.x;
  float4 v = ((const float4*)X)[idx];
  ushort4 o;
  o.x = f2bf(v.x); o.y = f2bf(v.y); o.z = f2bf(v.z); o.w = f2bf(v.w);
  ((ushort4*)Xb)[idx] = o;
}

// ---------------------------------------------------------------------------
// pv_trans: Pv [1023][8][64] fp32 -> Pvt [8*64][PVROWS] bf16 (g-contiguous,
// zero-padded rows g in [1023, PVROWS)). grid (17, 8).
// ---------------------------------------------------------------------------
__global__ __launch_bounds__(256) void pv_trans(const float* __restrict__ Pv,
                                                unsigned short* __restrict__ Pvt) {
  const int g0 = blockIdx.x * 64, hd0 = blockIdx.y * 64;
  __shared__ float t[64][65];
  const int tid = threadIdx.x;
#pragma unroll
  for (int u = 0; u < 16; ++u) {
    int idx = u * 256 + tid, r = idx >> 6, c = idx & 63;
    int g = g0 + r;
    t[r][c] = g < NUMREL ? Pv[(size_t)g * 512 + hd0 + c] : 0.f;
  }
  __syncthreads();
#pragma unroll
  for (int u = 0; u < 16; ++u) {
    int idx = u * 256 + tid, r = idx >> 6, c = idx & 63;
    int g = g0 + c;
    if (g < PVROWS) Pvt[(size_t)(hd0 + r) * PVROWS + g] = f2bf(t[c][r]);
  }
}

// ---------------------------------------------------------------------------
// wtrans: W[K,N] -> Wt[n][k] bf16. z=0..2: Wq/Wk/Wv; z=3: Wo hi; z=4: Wo lo.
// ---------------------------------------------------------------------------
__global__ __launch_bounds__(256) void wtrans(const float* __restrict__ Wq,
                                              const float* __restrict__ Wk,
                                              const float* __restrict__ Wv,
                                              const float* __restrict__ Wo,
                                              unsigned short* __restrict__ Wqt,
                                              unsigned short* __restrict__ Wkt,
                                              unsigned short* __restrict__ Wvt,
                                              unsigned short* __restrict__ Woth,
                                              unsigned short* __restrict__ Wotl) {
  const int z = blockIdx.z;
  const float* src = z == 0 ? Wq : z == 1 ? Wk : z == 2 ? Wv : Wo;
  unsigned short* dst = z == 0 ? Wqt : z == 1 ? Wkt : z == 2 ? Wvt : z == 3 ? Woth : Wotl;
  const int k0 = blockIdx.y * 32, n0 = blockIdx.x * 32;
  __shared__ float t[32][33];
  const int tid = threadIdx.x;
#pragma unroll
  for (int u = 0; u < 4; ++u) {
    int idx = u * 256 + tid, r = idx >> 5, c = idx & 31;
    t[r][c] = src[(size_t)(k0 + r) * DM + n0 + c];
  }
  __syncthreads();
#pragma unroll
  for (int u = 0; u < 4; ++u) {
    int idx = u * 256 + tid, r = idx >> 5, c = idx & 31;
    float v = t[c][r];
    unsigned short hv = f2bf(v);
    if (z == 4) hv = f2bf(v - bf2f(hv));
    dst[(size_t)(n0 + r) * DM + k0 + c] = hv;
  }
}

// ---------------------------------------------------------------------------
// gemm_qkv: z-FUSED bf16 MFMA, no LDS. Ping-pong pipeline; sched_barrier pins
// the next-step loads BEFORE the current MFMAs (compiler otherwise sinks them).
// ---------------------------------------------------------------------------
__global__ __launch_bounds__(256, 2) void gemm_qkv(const unsigned short* __restrict__ Xb,
                                                   const unsigned short* __restrict__ Wqt,
                                                   const unsigned short* __restrict__ Wkt,
                                                   const unsigned short* __restrict__ Wvt,
                                                   const float* __restrict__ bq,
                                                   const float* __restrict__ bk,
                                                   const float* __restrict__ bv,
                                                   unsigned short* __restrict__ Qb,
                                                   unsigned short* __restrict__ Kb,
                                                   unsigned short* __restrict__ Vt) {
  const int bm = blockIdx.y * 64, bn = blockIdx.x * 64;
  const int tid = threadIdx.x, w = tid >> 6, lane = tid & 63;
  const int lo = lane & 15, quad = lane >> 4;
  const int mt = (w >> 1) * 32, nt = (w & 1) * 32;

  const unsigned short* arow0 = Xb + (size_t)(bm + mt + lo) * DM + quad * 8;
  const unsigned short* arow1 = arow0 + 16 * DM;
  const size_t ncol0 = (size_t)(bn + nt + lo) * DM + quad * 8;
  const size_t ncol1 = ncol0 + 16 * DM;

  f32x4 acc[3][2][2] = {};
  bf16x8 af[2][2], bfq[2][2], bfk[2][2], bfv[2][2];

#define LOADK(buf, k0)                                                      \
  do {                                                                      \
    af[buf][0] = *(const bf16x8*)(arow0 + (k0));                            \
    af[buf][1] = *(const bf16x8*)(arow1 + (k0));                            \
    bfq[buf][0] = *(const bf16x8*)(Wqt + ncol0 + (k0));                     \
    bfq[buf][1] = *(const bf16x8*)(Wqt + ncol1 + (k0));                     \
    bfk[buf][0] = *(const bf16x8*)(Wkt + ncol0 + (k0));                     \
    bfk[buf][1] = *(const bf16x8*)(Wkt + ncol1 + (k0));                     \
    bfv[buf][0] = *(const bf16x8*)(Wvt + ncol0 + (k0));                     \
    bfv[buf][1] = *(const bf16x8*)(Wvt + ncol1 + (k0));                     \
  } while (0)

  LOADK(0, 0);
#pragma unroll
  for (int ks = 0; ks < 16; ++ks) {
    const int cur = ks & 1, nxt = cur ^ 1;
    if (ks < 15) LOADK(nxt, (ks + 1) * 32);
    __builtin_amdgcn_sched_barrier(0);  // keep prefetch issue ahead of MFMAs
#pragma unroll
    for (int i = 0; i < 2; ++i)
#pragma unroll
      for (int j = 0; j < 2; ++j) {
        acc[0][i][j] = __builtin_amdgcn_mfma_f32_16x16x32_bf16(af[cur][i], bfq[cur][j], acc[0][i][j], 0, 0, 0);
        acc[1][i][j] = __builtin_amdgcn_mfma_f32_16x16x32_bf16(af[cur][i], bfk[cur][j], acc[1][i][j], 0, 0, 0);
        acc[2][i][j] = __builtin_amdgcn_mfma_f32_16x16x32_bf16(af[cur][i], bfv[cur][j], acc[2][i][j], 0, 0, 0);
      }
  }
#undef LOADK

#pragma unroll
  for (int z = 0; z < 3; ++z) {
    const float* bias = z == 0 ? bq : z == 1 ? bk : bv;
#pragma unroll
    for (int i = 0; i < 2; ++i)
#pragma unroll
      for (int j = 0; j < 2; ++j) {
        int col = bn + nt + j * 16 + lo;
        int h = col >> 6, d = col & 63;
        float bv_ = bias[col];
#pragma unroll
        for (int r = 0; r < 4; ++r) {
          int row = bm + mt + i * 16 + quad * 4 + r;
          int b = row >> 9, is = row & 511;
          unsigned short val = f2bf(acc[z][i][j][r] + bv_);
          if (z == 2)
            Vt[((size_t)(b * Hh + h) * 64 + d) * 512 + is] = val;
          else if (z == 0)
            Qb[((size_t)(b * Hh + h) * Nseq + is) * 64 + d] = val;
          else
            Kb[((size_t)(b * Hh + h) * Nseq + is) * 64 + d] = val;
        }
      }
  }
}

// ---------------------------------------------------------------------------
// attn_fused: per block = (b, h, 16-row i-tile), XCD-swizzled 1-D grid.
// ALL K-fragments AND V-fragments issued at kernel entry (one batched latency
// window, pinned by sched_barrier so the compiler can't sink them); Pv
// fragments issued before the V-MFMA chain (hidden under it).
// ---------------------------------------------------------------------------
#define PSV 520  // pstrip row stride (elems): 4*odd -> 2-way aliasing (free)
#define PSH 552  // pshift row stride (elems): 4*odd -> 2-way aliasing (free)

__global__ __launch_bounds__(256, 2) void attn_fused(const unsigned short* __restrict__ Qb,
                                                     const unsigned short* __restrict__ Kb,
                                                     const unsigned short* __restrict__ Vt,
                                                     const float* __restrict__ Pk,
                                                     const unsigned short* __restrict__ Pvt,
                                                     unsigned short* __restrict__ Awh,
                                                     unsigned short* __restrict__ Awl) {
  // XCD-aware decode: bh % 8 == flat % 8
  const int flat = blockIdx.x;
  const int xcd = flat & 7;
  const int grp = flat >> 3;
  const int i0 = (grp & 31) * 16;
  const int bh = (grp >> 5) * 8 + xcd;   // b*8+h
  const int b = bh >> 3, h = bh & 7;
  const int tid = threadIdx.x;
  const int w = tid >> 6;
  const int lane = tid & 63;
  const int lo = lane & 15, quad = lane >> 4;

  __shared__ __align__(16) unsigned short pstrip[16 * PSV];
  __shared__ __align__(16) unsigned short pshift[16 * PSH];
  __shared__ float pk_lds[544];
  __shared__ float redm[4][16];
  __shared__ float redl[4][16];

  // zero pshift (pads beyond the diagonal band must be 0)
  int4 z4; z4.x = z4.y = z4.z = z4.w = 0;
  for (int c = tid; c < 16 * PSH / 8; c += 256) ((int4*)pshift)[c] = z4;
  for (int t = tid; t < 527; t += 256)
    pk_lds[t] = Pk[(size_t)(ZOFF - i0 - 15 + t) * Hh + h];

  // ---------------- Batched entry preloads (34 loads in flight) -----------
  const unsigned short* qbase = Qb + ((size_t)bh * Nseq + i0 + lo) * 64;
  bf16x8 qa0 = *(const bf16x8*)(qbase + quad * 8);
  bf16x8 qa1 = *(const bf16x8*)(qbase + 32 + quad * 8);

  const int jw = w * 128;
  bf16x8 kb0[8], kb1[8];
#pragma unroll
  for (int s = 0; s < 8; ++s) {
    const unsigned short* kbase = Kb + ((size_t)bh * Nseq + jw + s * 16 + lo) * 64;
    kb0[s] = *(const bf16x8*)(kbase + quad * 8);
    kb1[s] = *(const bf16x8*)(kbase + 32 + quad * 8);
  }
  const int d = w * 16 + lo;
  const unsigned short* vrow = Vt + ((size_t)bh * 64 + d) * 512;
  bf16x8 vbf[16];
#pragma unroll
  for (int ks = 0; ks < 16; ++ks)
    vbf[ks] = *(const bf16x8*)(vrow + ks * 32 + quad * 8);
  __builtin_amdgcn_sched_barrier(0);  // pin: all loads issued before compute
  __syncthreads();  // drains everything; pk_lds/pshift ready, all frags ready

  // ---------------- Phase 1: scores + softmax ----------------
  float sv[8][4];
  float mrow[4] = {-1e30f, -1e30f, -1e30f, -1e30f};
#pragma unroll
  for (int s = 0; s < 8; ++s) {
    f32x4 c = {0.f, 0.f, 0.f, 0.f};
    c = __builtin_amdgcn_mfma_f32_16x16x32_bf16(qa0, kb0[s], c, 0, 0, 0);
    c = __builtin_amdgcn_mfma_f32_16x16x32_bf16(qa1, kb1[s], c, 0, 0, 0);
    int j = jw + s * 16 + lo;
#pragma unroll
    for (int r = 0; r < 4; ++r) {
      int rl = quad * 4 + r;
      float v = (c[r] + pk_lds[j - rl + 15]) * 0.125f;
      sv[s][r] = v;
      mrow[r] = fmaxf(mrow[r], v);
    }
  }
#pragma unroll
  for (int m = 1; m <= 8; m <<= 1)
#pragma unroll
    for (int r = 0; r < 4; ++r) mrow[r] = fmaxf(mrow[r], __shfl_xor(mrow[r], m));
  if (lo == 0)
#pragma unroll
    for (int r = 0; r < 4; ++r) redm[w][quad * 4 + r] = mrow[r];
  __syncthreads();
  float mfin[4];
#pragma unroll
  for (int r = 0; r < 4; ++r) {
    int rl = quad * 4 + r;
    mfin[r] = fmaxf(fmaxf(redm[0][rl], redm[1][rl]), fmaxf(redm[2][rl], redm[3][rl]));
  }
  float lrow[4] = {0.f, 0.f, 0.f, 0.f};
#pragma unroll
  for (int s = 0; s < 8; ++s)
#pragma unroll
    for (int r = 0; r < 4; ++r) {
      float e = __expf(sv[s][r] - mfin[r]);
      sv[s][r] = e;
      lrow[r] += e;
    }
#pragma unroll
  for (int m = 1; m <= 8; m <<= 1)
#pragma unroll
    for (int r = 0; r < 4; ++r) lrow[r] += __shfl_xor(lrow[r], m);
  if (lo == 0)
#pragma unroll
    for (int r = 0; r < 4; ++r) redl[w][quad * 4 + r] = lrow[r];
  __syncthreads();
#pragma unroll
  for (int r = 0; r < 4; ++r) {
    int rl = quad * 4 + r;
    float linv = 1.f / (redl[0][rl] + redl[1][rl] + redl[2][rl] + redl[3][rl]);
#pragma unroll
    for (int s = 0; s < 8; ++s) {
      int j = jw + s * 16 + lo;
      unsigned short pb = f2bf(sv[s][r] * linv);
      pstrip[rl * PSV + j] = pb;
      pshift[rl * PSH + j - rl + 15] = pb;
    }
  }
  __syncthreads();

  // ---------------- Phase 2: P@V + P'@Pv ----------------
  // Issue all Pv B-fragments now; they land while the V-chain runs.
  const int tminrow = ZOFF - i0 - 15;  // multiple of 16, >= 0
  const unsigned short* pvrow = Pvt + ((size_t)h * 64 + d) * PVROWS + tminrow;
  bf16x8 pvf[17];
#pragma unroll
  for (int ks = 0; ks < 17; ++ks)
    pvf[ks] = *(const bf16x8*)(pvrow + ks * 32 + quad * 8);
  __builtin_amdgcn_sched_barrier(0);  // pin: Pv loads issued before V-chain

  f32x4 oacc = {0.f, 0.f, 0.f, 0.f};
#pragma unroll
  for (int ks = 0; ks < 16; ++ks) {
    bf16x8 pa = *(const bf16x8*)(pstrip + lo * PSV + ks * 32 + quad * 8);
    oacc = __builtin_amdgcn_mfma_f32_16x16x32_bf16(pa, vbf[ks], oacc, 0, 0, 0);
  }
#pragma unroll
  for (int ks = 0; ks < 17; ++ks) {
    bf16x8 pa = *(const bf16x8*)(pshift + lo * PSH + ks * 32 + quad * 8);
    oacc = __builtin_amdgcn_mfma_f32_16x16x32_bf16(pa, pvf[ks], oacc, 0, 0, 0);
  }

  // write Aw hi/lo bf16, layout [b*N+i][H*64]
#pragma unroll
  for (int r = 0; r < 4; ++r) {
    int i = i0 + quad * 4 + r;
    float o = oacc[r];
    unsigned short hi = f2bf(o);
    unsigned short lov = f2bf(o - bf2f(hi));
    size_t off = ((size_t)(b * Nseq + i)) * (Hh * 64) + h * 64 + d;
    Awh[off] = hi;
    Awl[off] = lov;
  }
}

// ---------------------------------------------------------------------------
// gemm_final: split-bf16 (3-term) MFMA GEMM. out = Ah@Bh + Ah@Bl + Al@Bh + bo
// ---------------------------------------------------------------------------
__global__ __launch_bounds__(256, 2) void gemm_final(const unsigned short* __restrict__ Ah,
                                                     const unsigned short* __restrict__ Al,
                                                     const unsigned short* __restrict__ Bh,
                                                     const unsigned short* __restrict__ Bl,
                                                     const float* __restrict__ bo,
                                                     float* __restrict__ out) {
  const int bm = blockIdx.y * 64, bn = blockIdx.x * 64;
  const int tid = threadIdx.x, w = tid >> 6, lane = tid & 63;
  const int lo = lane & 15, quad = lane >> 4;
  const int mt = (w >> 1) * 32, nt = (w & 1) * 32;

  const size_t arow0 = (size_t)(bm + mt + lo) * DM + quad * 8;
  const size_t arow1 = arow0 + 16 * DM;
  const size_t ncol0 = (size_t)(bn + nt + lo) * DM + quad * 8;
  const size_t ncol1 = ncol0 + 16 * DM;

  f32x4 acc[2][2] = {};
  bf16x8 ah[2][2], al[2][2], bh[2][2], bl[2][2];

#define LOADK2(buf, k0)                                       \
  do {                                                        \
    ah[buf][0] = *(const bf16x8*)(Ah + arow0 + (k0));         \
    ah[buf][1] = *(const bf16x8*)(Ah + arow1 + (k0));         \
    al[buf][0] = *(const bf16x8*)(Al + arow0 + (k0));         \
    al[buf][1] = *(const bf16x8*)(Al + arow1 + (k0));         \
    bh[buf][0] = *(const bf16x8*)(Bh + ncol0 + (k0));         \
    bh[buf][1] = *(const bf16x8*)(Bh + ncol1 + (k0));         \
    bl[buf][0] = *(const bf16x8*)(Bl + ncol0 + (k0));         \
    bl[buf][1] = *(const bf16x8*)(Bl + ncol1 + (k0));         \
  } while (0)

  LOADK2(0, 0);
#pragma unroll
  for (int ks = 0; ks < 16; ++ks) {
    const int cur = ks & 1, nxt = cur ^ 1;
    if (ks < 15) LOADK2(nxt, (ks + 1) * 32);
    __builtin_amdgcn_sched_barrier(0);  // keep prefetch issue ahead of MFMAs
#pragma unroll
    for (int i = 0; i < 2; ++i)
#pragma unroll
      for (int j = 0; j < 2; ++j) {
        acc[i][j] = __builtin_amdgcn_mfma_f32_16x16x32_bf16(ah[cur][i], bh[cur][j], acc[i][j], 0, 0, 0);
        acc[i][j] = __builtin_amdgcn_mfma_f32_16x16x32_bf16(ah[cur][i], bl[cur][j], acc[i][j], 0, 0, 0);
        acc[i][j] = __builtin_amdgcn_mfma_f32_16x16x32_bf16(al[cur][i], bh[cur][j], acc[i][j], 0, 0, 0);
      }
  }
#undef LOADK2

#pragma unroll
  for (int i = 0; i < 2; ++i)
#pragma unroll
    for (int j = 0; j < 2; ++j) {
      int col = bn + nt + j * 16 + lo;
      float bb = bo[col];
#pragma unroll
      for (int r = 0; r < 4; ++r) {
        int row = bm + mt + i * 16 + quad * 4 + r;
        out[(size_t)row * DM + col] = acc[i][j][r] + bb;
      }
    }
}

// ---------------------------------------------------------------------------
extern "C" void kernel_launch(void* const* d_in, const int* in_sizes, int n_in,
                              void* d_out, int out_size, void* d_ws, size_t ws_size,
                              hipStream_t stream) {
  const float* X  = (const float*)d_in[0];
  const float* Wq = (const float*)d_in[1];
  const float* bq = (const float*)d_in[2];
  const float* Wk = (const float*)d_in[3];
  const float* bk = (const float*)d_in[4];
  const float* Wv = (const float*)d_in[5];
  const float* bv = (const float*)d_in[6];
  const float* Wo = (const float*)d_in[7];
  const float* bo = (const float*)d_in[8];
  const float* Pk = (const float*)d_in[9];
  const float* Pv = (const float*)d_in[10];
  float* out = (float*)d_out;

  char* p = (char*)d_ws;
  const size_t szX   = (size_t)Bc * Nseq * DM * 2;          // 4 MB
  const size_t szW   = (size_t)DM * DM * 2;                 // 512 KB
  const size_t szPvt = (size_t)Hh * 64 * PVROWS * 2;        // ~1 MB
  const size_t szQKV = (size_t)Bc * Hh * Nseq * 64 * 2;     // 4 MB
  unsigned short* Xb   = (unsigned short*)p; p += szX;
  unsigned short* Wqt  = (unsigned short*)p; p += szW;
  unsigned short* Wkt  = (unsigned short*)p; p += szW;
  unsigned short* Wvt  = (unsigned short*)p; p += szW;
  unsigned short* Woth = (unsigned short*)p; p += szW;
  unsigned short* Wotl = (unsigned short*)p; p += szW;
  unsigned short* Pvt  = (unsigned short*)p; p += szPvt;
  unsigned short* Qb   = (unsigned short*)p; p += szQKV;
  unsigned short* Kb   = (unsigned short*)p; p += szQKV;
  unsigned short* Vt   = (unsigned short*)p; p += szQKV;
  unsigned short* Awh  = (unsigned short*)p; p += szX;
  unsigned short* Awl  = (unsigned short*)p; p += szX;

  dim3 blk(256);
  prep_cvt<<<dim3(2048), blk, 0, stream>>>(X, Xb);
  pv_trans<<<dim3(17, 8), blk, 0, stream>>>(Pv, Pvt);
  wtrans<<<dim3(16, 16, 5), blk, 0, stream>>>(Wq, Wk, Wv, Wo, Wqt, Wkt, Wvt, Woth, Wotl);
  gemm_qkv<<<dim3(8, 64), blk, 0, stream>>>(Xb, Wqt, Wkt, Wvt, bq, bk, bv, Qb, Kb, Vt);
  attn_fused<<<dim3(2048), blk, 0, stream>>>(Qb, Kb, Vt, Pk, Pvt, Awh, Awl);
  gemm_final<<<dim3(8, 64), blk, 0, stream>>>(Awh, Awl, Woth, Wotl, bo, out);
}

// Round 8
// 157.547 us; speedup vs baseline: 1.2506x; 1.2429x over previous
//
#include <hip/hip_runtime.h>
#include <math.h>

#define Bc 8
#define Nseq 512
#define DM 512
#define Hh 8
#define NUMREL 1023
#define ZOFF 511     // NUMREL/2
#define PVROWS 1040  // Pvt padded g-extent

typedef short bf16x8 __attribute__((ext_vector_type(8)));
typedef float f32x4 __attribute__((ext_vector_type(4)));

__device__ __forceinline__ unsigned short f2bf(float f) {
  unsigned u = __builtin_bit_cast(unsigned, f);
  u += 0x7fff + ((u >> 16) & 1);  // RNE
  return (unsigned short)(u >> 16);
}
__device__ __forceinline__ float bf2f(unsigned short h) {
  unsigned u = ((unsigned)h) << 16;
  return __builtin_bit_cast(float, u);
}

// async global->LDS, 16 B per lane; LDS dest is wave-uniform base + lane*16.
typedef __attribute__((address_space(3))) unsigned int as3_uint;
typedef __attribute__((address_space(1))) const unsigned int as1_uint;
__device__ __forceinline__ void gl_lds16(const void* g, void* l) {
  __builtin_amdgcn_global_load_lds((as1_uint*)g, (as3_uint*)l, 16, 0, 0);
}

// ---------------------------------------------------------------------------
// prep_xF: X [4096][512] fp32 -> A-frag-major bf16:
// XbF[mc][kf][l][e] = X[mc*16 + (l&15)][kf*32 + (l>>4)*8 + e]
// One wave per row; coalesced 2 KB row reads. grid 1024.
// ---------------------------------------------------------------------------
__global__ __launch_bounds__(256) void prep_xF(const float* __restrict__ X,
                                               unsigned short* __restrict__ XbF) {
  const int w = threadIdx.x >> 6, lane = threadIdx.x & 63;
  const int r = blockIdx.x * 4 + w;
  const float* src = X + (size_t)r * DM + lane * 8;
  float4 a = *(const float4*)src;
  float4 b = *(const float4*)(src + 4);
  ushort4 o0, o1;
  o0.x = f2bf(a.x); o0.y = f2bf(a.y); o0.z = f2bf(a.z); o0.w = f2bf(a.w);
  o1.x = f2bf(b.x); o1.y = f2bf(b.y); o1.z = f2bf(b.z); o1.w = f2bf(b.w);
  const int mc = r >> 4, kf = lane >> 2, l = (lane & 3) * 16 + (r & 15);
  size_t flat = (((size_t)mc * 16 + kf) * 64 + l) * 8;
  *(ushort4*)(XbF + flat) = o0;
  *(ushort4*)(XbF + flat + 4) = o1;
}

// ---------------------------------------------------------------------------
// prep_wF: W [K=512][N=512] fp32 -> B-frag-major bf16:
// WF[nc][kf][l][e] = W[kf*32 + (l>>4)*8 + e][nc*16 + (l&15)]
// z=0..2: Wq/Wk/Wv; z=3: Wo hi; z=4: Wo lo. grid (16,16,5).
// ---------------------------------------------------------------------------
__global__ __launch_bounds__(256) void prep_wF(const float* __restrict__ Wq,
                                               const float* __restrict__ Wk,
                                               const float* __restrict__ Wv,
                                               const float* __restrict__ Wo,
                                               unsigned short* __restrict__ WqF,
                                               unsigned short* __restrict__ WkF,
                                               unsigned short* __restrict__ WvF,
                                               unsigned short* __restrict__ WoFh,
                                               unsigned short* __restrict__ WoFl) {
  const int z = blockIdx.z;
  const float* src = z == 0 ? Wq : z == 1 ? Wk : z == 2 ? Wv : Wo;
  unsigned short* dst = z == 0 ? WqF : z == 1 ? WkF : z == 2 ? WvF : z == 3 ? WoFh : WoFl;
  const int k0 = blockIdx.y * 32, n0 = blockIdx.x * 32;
  __shared__ float t[32][33];
  const int tid = threadIdx.x;
#pragma unroll
  for (int u = 0; u < 4; ++u) {
    int idx = u * 256 + tid, r = idx >> 5, c = idx & 31;
    t[r][c] = src[(size_t)(k0 + r) * DM + n0 + c];
  }
  __syncthreads();
  const int ncl = tid >> 7, l = (tid >> 1) & 63, eh = tid & 1;
  const int nl = ncl * 16 + (l & 15);
  const int klb = (l >> 4) * 8 + eh * 4;
  ushort4 o;
  {
    float v0 = t[klb + 0][nl], v1 = t[klb + 1][nl], v2 = t[klb + 2][nl], v3 = t[klb + 3][nl];
    unsigned short h0 = f2bf(v0), h1 = f2bf(v1), h2 = f2bf(v2), h3 = f2bf(v3);
    if (z == 4) {
      h0 = f2bf(v0 - bf2f(h0)); h1 = f2bf(v1 - bf2f(h1));
      h2 = f2bf(v2 - bf2f(h2)); h3 = f2bf(v3 - bf2f(h3));
    }
    o.x = h0; o.y = h1; o.z = h2; o.w = h3;
  }
  size_t flat = (((size_t)((n0 >> 4) + ncl) * 16 + (k0 >> 5)) * 64 + l) * 8 + eh * 4;
  *(ushort4*)(dst + flat) = o;
}

// ---------------------------------------------------------------------------
// pv_trans: Pv [1023][8][64] fp32 -> Pvt [8*64][PVROWS] bf16 (unchanged).
// ---------------------------------------------------------------------------
__global__ __launch_bounds__(256) void pv_trans(const float* __restrict__ Pv,
                                                unsigned short* __restrict__ Pvt) {
  const int g0 = blockIdx.x * 64, hd0 = blockIdx.y * 64;
  __shared__ float t[64][65];
  const int tid = threadIdx.x;
#pragma unroll
  for (int u = 0; u < 16; ++u) {
    int idx = u * 256 + tid, r = idx >> 6, c = idx & 63;
    int g = g0 + r;
    t[r][c] = g < NUMREL ? Pv[(size_t)g * 512 + hd0 + c] : 0.f;
  }
  __syncthreads();
#pragma unroll
  for (int u = 0; u < 16; ++u) {
    int idx = u * 256 + tid, r = idx >> 6, c = idx & 63;
    int g = g0 + c;
    if (g < PVROWS) Pvt[(size_t)(hd0 + r) * PVROWS + g] = f2bf(t[c][r]);
  }
}

// ---------------------------------------------------------------------------
// gemm_qkv: z-fused, frag-major, double-buffered global_load_lds staging.
// LDS per step: 16 chunks x 1 KB: [A mc0..+3][Bq nc0..+3][Bk][Bv].
// grid 512 (XCD-banded: xcd = flat&7 owns a 512-row A band).
// ---------------------------------------------------------------------------
__global__ __launch_bounds__(256, 2) void gemm_qkv(const unsigned short* __restrict__ XbF,
                                                   const unsigned short* __restrict__ WqF,
                                                   const unsigned short* __restrict__ WkF,
                                                   const unsigned short* __restrict__ WvF,
                                                   const float* __restrict__ bq,
                                                   const float* __restrict__ bk,
                                                   const float* __restrict__ bv,
                                                   unsigned short* __restrict__ Qb,
                                                   unsigned short* __restrict__ Kb,
                                                   unsigned short* __restrict__ Vt) {
  const int flat = blockIdx.x;
  const int xcd = flat & 7, g = flat >> 3;
  const int by = xcd * 8 + (g & 7), bx = g >> 3;
  const int bm = by * 64, bn = bx * 64;
  const int mc0 = bm >> 4, nc0 = bn >> 4;
  const int tid = threadIdx.x, w = tid >> 6, lane = tid & 63;
  const int lo = lane & 15, quad = lane >> 4;
  const int mh = (w >> 1) * 2, nh = (w & 1) * 2;

  __shared__ __align__(16) unsigned short stg[2][16 * 512];

  // wave w stages 4 chunks from ONE source array
  const unsigned short* srcArr = w == 0 ? XbF : w == 1 ? WqF : w == 2 ? WkF : WvF;
  const int rowbase = (w == 0) ? mc0 : nc0;

#define STAGE(buf, kf)                                                         \
  do {                                                                         \
    _Pragma("unroll") for (int t = 0; t < 4; ++t) {                            \
      gl_lds16(srcArr + (((size_t)(rowbase + t) * 16 + (kf)) * 512) + lane * 8,\
               &stg[buf][(w * 4 + t) * 512]);                                  \
    }                                                                          \
  } while (0)

  f32x4 acc[3][2][2] = {};
  STAGE(0, 0);
  int cur = 0;
#pragma unroll
  for (int kf = 0; kf < 16; ++kf) {
    __syncthreads();  // drains vmcnt (stage done) + lgkm (prev reads done)
    if (kf < 15) STAGE(cur ^ 1, kf + 1);
    bf16x8 af[2], bq_[2], bk_[2], bv_[2];
#pragma unroll
    for (int i = 0; i < 2; ++i)
      af[i] = *(const bf16x8*)(&stg[cur][(mh + i) * 512 + lane * 8]);
#pragma unroll
    for (int j = 0; j < 2; ++j) {
      bq_[j] = *(const bf16x8*)(&stg[cur][(4 + nh + j) * 512 + lane * 8]);
      bk_[j] = *(const bf16x8*)(&stg[cur][(8 + nh + j) * 512 + lane * 8]);
      bv_[j] = *(const bf16x8*)(&stg[cur][(12 + nh + j) * 512 + lane * 8]);
    }
#pragma unroll
    for (int i = 0; i < 2; ++i)
#pragma unroll
      for (int j = 0; j < 2; ++j) {
        acc[0][i][j] = __builtin_amdgcn_mfma_f32_16x16x32_bf16(af[i], bq_[j], acc[0][i][j], 0, 0, 0);
        acc[1][i][j] = __builtin_amdgcn_mfma_f32_16x16x32_bf16(af[i], bk_[j], acc[1][i][j], 0, 0, 0);
        acc[2][i][j] = __builtin_amdgcn_mfma_f32_16x16x32_bf16(af[i], bv_[j], acc[2][i][j], 0, 0, 0);
      }
    cur ^= 1;
  }
#undef STAGE

  const int mt = (w >> 1) * 32, nt = (w & 1) * 32;
#pragma unroll
  for (int z = 0; z < 3; ++z) {
    const float* bias = z == 0 ? bq : z == 1 ? bk : bv;
#pragma unroll
    for (int i = 0; i < 2; ++i)
#pragma unroll
      for (int j = 0; j < 2; ++j) {
        int col = bn + nt + j * 16 + lo;
        int h = col >> 6, d = col & 63;
        float bv2 = bias[col];
#pragma unroll
        for (int r = 0; r < 4; ++r) {
          int row = bm + mt + i * 16 + quad * 4 + r;
          int b = row >> 9, is = row & 511;
          unsigned short val = f2bf(acc[z][i][j][r] + bv2);
          if (z == 2)
            Vt[((size_t)(b * Hh + h) * 64 + d) * 512 + is] = val;
          else if (z == 0)
            Qb[((size_t)(b * Hh + h) * Nseq + is) * 64 + d] = val;
          else
            Kb[((size_t)(b * Hh + h) * Nseq + is) * 64 + d] = val;
        }
      }
  }
}

// ---------------------------------------------------------------------------
// attn_fused: unchanged body (r7); epilogue now writes A-frag-major AwF hi/lo.
// ---------------------------------------------------------------------------
#define PSV 520
#define PSH 552

__global__ __launch_bounds__(256, 2) void attn_fused(const unsigned short* __restrict__ Qb,
                                                     const unsigned short* __restrict__ Kb,
                                                     const unsigned short* __restrict__ Vt,
                                                     const float* __restrict__ Pk,
                                                     const unsigned short* __restrict__ Pvt,
                                                     unsigned short* __restrict__ AwFh,
                                                     unsigned short* __restrict__ AwFl) {
  const int flat = blockIdx.x;
  const int xcd = flat & 7;
  const int grp = flat >> 3;
  const int i0 = (grp & 31) * 16;
  const int bh = (grp >> 5) * 8 + xcd;
  const int b = bh >> 3, h = bh & 7;
  const int tid = threadIdx.x;
  const int w = tid >> 6;
  const int lane = tid & 63;
  const int lo = lane & 15, quad = lane >> 4;

  __shared__ __align__(16) unsigned short pstrip[16 * PSV];
  __shared__ __align__(16) unsigned short pshift[16 * PSH];
  __shared__ float pk_lds[544];
  __shared__ float redm[4][16];
  __shared__ float redl[4][16];

  int4 z4; z4.x = z4.y = z4.z = z4.w = 0;
  for (int c = tid; c < 16 * PSH / 8; c += 256) ((int4*)pshift)[c] = z4;
  for (int t = tid; t < 527; t += 256)
    pk_lds[t] = Pk[(size_t)(ZOFF - i0 - 15 + t) * Hh + h];

  const unsigned short* qbase = Qb + ((size_t)bh * Nseq + i0 + lo) * 64;
  bf16x8 qa0 = *(const bf16x8*)(qbase + quad * 8);
  bf16x8 qa1 = *(const bf16x8*)(qbase + 32 + quad * 8);

  const int jw = w * 128;
  bf16x8 kb0[8], kb1[8];
#pragma unroll
  for (int s = 0; s < 8; ++s) {
    const unsigned short* kbase = Kb + ((size_t)bh * Nseq + jw + s * 16 + lo) * 64;
    kb0[s] = *(const bf16x8*)(kbase + quad * 8);
    kb1[s] = *(const bf16x8*)(kbase + 32 + quad * 8);
  }
  const int d = w * 16 + lo;
  const unsigned short* vrow = Vt + ((size_t)bh * 64 + d) * 512;
  bf16x8 vbf[16];
#pragma unroll
  for (int ks = 0; ks < 16; ++ks)
    vbf[ks] = *(const bf16x8*)(vrow + ks * 32 + quad * 8);
  __builtin_amdgcn_sched_barrier(0);
  __syncthreads();

  float sv[8][4];
  float mrow[4] = {-1e30f, -1e30f, -1e30f, -1e30f};
#pragma unroll
  for (int s = 0; s < 8; ++s) {
    f32x4 c = {0.f, 0.f, 0.f, 0.f};
    c = __builtin_amdgcn_mfma_f32_16x16x32_bf16(qa0, kb0[s], c, 0, 0, 0);
    c = __builtin_amdgcn_mfma_f32_16x16x32_bf16(qa1, kb1[s], c, 0, 0, 0);
    int j = jw + s * 16 + lo;
#pragma unroll
    for (int r = 0; r < 4; ++r) {
      int rl = quad * 4 + r;
      float v = (c[r] + pk_lds[j - rl + 15]) * 0.125f;
      sv[s][r] = v;
      mrow[r] = fmaxf(mrow[r], v);
    }
  }
#pragma unroll
  for (int m = 1; m <= 8; m <<= 1)
#pragma unroll
    for (int r = 0; r < 4; ++r) mrow[r] = fmaxf(mrow[r], __shfl_xor(mrow[r], m));
  if (lo == 0)
#pragma unroll
    for (int r = 0; r < 4; ++r) redm[w][quad * 4 + r] = mrow[r];
  __syncthreads();
  float mfin[4];
#pragma unroll
  for (int r = 0; r < 4; ++r) {
    int rl = quad * 4 + r;
    mfin[r] = fmaxf(fmaxf(redm[0][rl], redm[1][rl]), fmaxf(redm[2][rl], redm[3][rl]));
  }
  float lrow[4] = {0.f, 0.f, 0.f, 0.f};
#pragma unroll
  for (int s = 0; s < 8; ++s)
#pragma unroll
    for (int r = 0; r < 4; ++r) {
      float e = __expf(sv[s][r] - mfin[r]);
      sv[s][r] = e;
      lrow[r] += e;
    }
#pragma unroll
  for (int m = 1; m <= 8; m <<= 1)
#pragma unroll
    for (int r = 0; r < 4; ++r) lrow[r] += __shfl_xor(lrow[r], m);
  if (lo == 0)
#pragma unroll
    for (int r = 0; r < 4; ++r) redl[w][quad * 4 + r] = lrow[r];
  __syncthreads();
#pragma unroll
  for (int r = 0; r < 4; ++r) {
    int rl = quad * 4 + r;
    float linv = 1.f / (redl[0][rl] + redl[1][rl] + redl[2][rl] + redl[3][rl]);
#pragma unroll
    for (int s = 0; s < 8; ++s) {
      int j = jw + s * 16 + lo;
      unsigned short pb = f2bf(sv[s][r] * linv);
      pstrip[rl * PSV + j] = pb;
      pshift[rl * PSH + j - rl + 15] = pb;
    }
  }
  __syncthreads();

  const int tminrow = ZOFF - i0 - 15;
  const unsigned short* pvrow = Pvt + ((size_t)h * 64 + d) * PVROWS + tminrow;
  bf16x8 pvf[17];
#pragma unroll
  for (int ks = 0; ks < 17; ++ks)
    pvf[ks] = *(const bf16x8*)(pvrow + ks * 32 + quad * 8);
  __builtin_amdgcn_sched_barrier(0);

  f32x4 oacc = {0.f, 0.f, 0.f, 0.f};
#pragma unroll
  for (int ks = 0; ks < 16; ++ks) {
    bf16x8 pa = *(const bf16x8*)(pstrip + lo * PSV + ks * 32 + quad * 8);
    oacc = __builtin_amdgcn_mfma_f32_16x16x32_bf16(pa, vbf[ks], oacc, 0, 0, 0);
  }
#pragma unroll
  for (int ks = 0; ks < 17; ++ks) {
    bf16x8 pa = *(const bf16x8*)(pshift + lo * PSH + ks * 32 + quad * 8);
    oacc = __builtin_amdgcn_mfma_f32_16x16x32_bf16(pa, pvf[ks], oacc, 0, 0, 0);
  }

  // epilogue: A-frag-major AwF[mc][kf][l][e], row = b*512+i, col = h*64+d
  const int mc = b * 32 + (i0 >> 4);
  const int kf = h * 2 + (w >> 1);
  const int lhi = ((w & 1) * 2 + (lo >> 3)) * 16;
#pragma unroll
  for (int r = 0; r < 4; ++r) {
    float o = oacc[r];
    unsigned short hi = f2bf(o);
    unsigned short lov = f2bf(o - bf2f(hi));
    size_t fl = (((size_t)mc * 16 + kf) * 64 + lhi + quad * 4 + r) * 8 + (lo & 7);
    AwFh[fl] = hi;
    AwFl[fl] = lov;
  }
}

// ---------------------------------------------------------------------------
// gemm_final: split-bf16 3-term, frag-major, double-buffered LDS staging.
// LDS per step: 16 chunks: [Ah mc0..+3][Al][Bh nc0..+3][Bl]. grid 512.
// ---------------------------------------------------------------------------
__global__ __launch_bounds__(256, 2) void gemm_final(const unsigned short* __restrict__ AhF,
                                                     const unsigned short* __restrict__ AlF,
                                                     const unsigned short* __restrict__ BhF,
                                                     const unsigned short* __restrict__ BlF,
                                                     const float* __restrict__ bo,
                                                     float* __restrict__ out) {
  const int flat = blockIdx.x;
  const int xcd = flat & 7, g = flat >> 3;
  const int by = xcd * 8 + (g & 7), bx = g >> 3;
  const int bm = by * 64, bn = bx * 64;
  const int mc0 = bm >> 4, nc0 = bn >> 4;
  const int tid = threadIdx.x, w = tid >> 6, lane = tid & 63;
  const int lo = lane & 15, quad = lane >> 4;
  const int mh = (w >> 1) * 2, nh = (w & 1) * 2;

  __shared__ __align__(16) unsigned short stg[2][16 * 512];

  const unsigned short* srcArr = w == 0 ? AhF : w == 1 ? AlF : w == 2 ? BhF : BlF;
  const int rowbase = (w < 2) ? mc0 : nc0;

#define STAGE2(buf, kf)                                                        \
  do {                                                                         \
    _Pragma("unroll") for (int t = 0; t < 4; ++t) {                            \
      gl_lds16(srcArr + (((size_t)(rowbase + t) * 16 + (kf)) * 512) + lane * 8,\
               &stg[buf][(w * 4 + t) * 512]);                                  \
    }                                                                          \
  } while (0)

  f32x4 acc[2][2] = {};
  STAGE2(0, 0);
  int cur = 0;
#pragma unroll
  for (int kf = 0; kf < 16; ++kf) {
    __syncthreads();
    if (kf < 15) STAGE2(cur ^ 1, kf + 1);
    bf16x8 ah[2], al[2], bh[2], bl[2];
#pragma unroll
    for (int i = 0; i < 2; ++i) {
      ah[i] = *(const bf16x8*)(&stg[cur][(mh + i) * 512 + lane * 8]);
      al[i] = *(const bf16x8*)(&stg[cur][(4 + mh + i) * 512 + lane * 8]);
    }
#pragma unroll
    for (int j = 0; j < 2; ++j) {
      bh[j] = *(const bf16x8*)(&stg[cur][(8 + nh + j) * 512 + lane * 8]);
      bl[j] = *(const bf16x8*)(&stg[cur][(12 + nh + j) * 512 + lane * 8]);
    }
#pragma unroll
    for (int i = 0; i < 2; ++i)
#pragma unroll
      for (int j = 0; j < 2; ++j) {
        acc[i][j] = __builtin_amdgcn_mfma_f32_16x16x32_bf16(ah[i], bh[j], acc[i][j], 0, 0, 0);
        acc[i][j] = __builtin_amdgcn_mfma_f32_16x16x32_bf16(ah[i], bl[j], acc[i][j], 0, 0, 0);
        acc[i][j] = __builtin_amdgcn_mfma_f32_16x16x32_bf16(al[i], bh[j], acc[i][j], 0, 0, 0);
      }
    cur ^= 1;
  }
#undef STAGE2

  const int mt = (w >> 1) * 32, nt = (w & 1) * 32;
#pragma unroll
  for (int i = 0; i < 2; ++i)
#pragma unroll
    for (int j = 0; j < 2; ++j) {
      int col = bn + nt + j * 16 + lo;
      float bb = bo[col];
#pragma unroll
      for (int r = 0; r < 4; ++r) {
        int row = bm + mt + i * 16 + quad * 4 + r;
        out[(size_t)row * DM + col] = acc[i][j][r] + bb;
      }
    }
}

// ---------------------------------------------------------------------------
extern "C" void kernel_launch(void* const* d_in, const int* in_sizes, int n_in,
                              void* d_out, int out_size, void* d_ws, size_t ws_size,
                              hipStream_t stream) {
  const float* X  = (const float*)d_in[0];
  const float* Wq = (const float*)d_in[1];
  const float* bq = (const float*)d_in[2];
  const float* Wk = (const float*)d_in[3];
  const float* bk = (const float*)d_in[4];
  const float* Wv = (const float*)d_in[5];
  const float* bv = (const float*)d_in[6];
  const float* Wo = (const float*)d_in[7];
  const float* bo = (const float*)d_in[8];
  const float* Pk = (const float*)d_in[9];
  const float* Pv = (const float*)d_in[10];
  float* out = (float*)d_out;

  char* p = (char*)d_ws;
  const size_t szX   = (size_t)Bc * Nseq * DM * 2;        // 4 MB (frag-major)
  const size_t szW   = (size_t)DM * DM * 2;               // 512 KB
  const size_t szPvt = (size_t)Hh * 64 * PVROWS * 2;      // ~1 MB
  const size_t szQKV = (size_t)Bc * Hh * Nseq * 64 * 2;   // 4 MB
  unsigned short* XbF  = (unsigned short*)p; p += szX;
  unsigned short* WqF  = (unsigned short*)p; p += szW;
  unsigned short* WkF  = (unsigned short*)p; p += szW;
  unsigned short* WvF  = (unsigned short*)p; p += szW;
  unsigned short* WoFh = (unsigned short*)p; p += szW;
  unsigned short* WoFl = (unsigned short*)p; p += szW;
  unsigned short* Pvt  = (unsigned short*)p; p += szPvt;
  unsigned short* Qb   = (unsigned short*)p; p += szQKV;
  unsigned short* Kb   = (unsigned short*)p; p += szQKV;
  unsigned short* Vt   = (unsigned short*)p; p += szQKV;
  unsigned short* AwFh = (unsigned short*)p; p += szX;
  unsigned short* AwFl = (unsigned short*)p; p += szX;

  dim3 blk(256);
  prep_xF<<<dim3(1024), blk, 0, stream>>>(X, XbF);
  pv_trans<<<dim3(17, 8), blk, 0, stream>>>(Pv, Pvt);
  prep_wF<<<dim3(16, 16, 5), blk, 0, stream>>>(Wq, Wk, Wv, Wo, WqF, WkF, WvF, WoFh, WoFl);
  gemm_qkv<<<dim3(512), blk, 0, stream>>>(XbF, WqF, WkF, WvF, bq, bk, bv, Qb, Kb, Vt);
  attn_fused<<<dim3(2048), blk, 0, stream>>>(Qb, Kb, Vt, Pk, Pvt, AwFh, AwFl);
  gemm_final<<<dim3(512), blk, 0, stream>>>(AwFh, AwFl, WoFh, WoFl, bo, out);
}

// Round 9
// 156.899 us; speedup vs baseline: 1.2557x; 1.0041x over previous
//
#include <hip/hip_runtime.h>
#include <math.h>

#define Bc 8
#define Nseq 512
#define DM 512
#define Hh 8
#define NUMREL 1023
#define ZOFF 511     // NUMREL/2
#define STR 568      // pstrip row stride (shorts): 16-apron + 512 + tail zeros

typedef short bf16x8 __attribute__((ext_vector_type(8)));
typedef float f32x4 __attribute__((ext_vector_type(4)));

__device__ __forceinline__ unsigned short f2bf(float f) {
  unsigned u = __builtin_bit_cast(unsigned, f);
  u += 0x7fff + ((u >> 16) & 1);  // RNE
  return (unsigned short)(u >> 16);
}
__device__ __forceinline__ float bf2f(unsigned short h) {
  unsigned u = ((unsigned)h) << 16;
  return __builtin_bit_cast(float, u);
}

// async global->LDS, 16 B per lane; LDS dest = wave-uniform base + lane*16.
typedef __attribute__((address_space(3))) unsigned int as3_uint;
typedef __attribute__((address_space(1))) const unsigned int as1_uint;
__device__ __forceinline__ void gl_lds16(const void* g, void* l) {
  __builtin_amdgcn_global_load_lds((as1_uint*)g, (as3_uint*)l, 16, 0, 0);
}

// manual waitcnt helpers (sched_barrier-pinned so nothing floats across)
#define WAITVM(n)                                     \
  do {                                                \
    __builtin_amdgcn_sched_barrier(0);                \
    __builtin_amdgcn_s_waitcnt(0x0F70 | (n));         \
    __builtin_amdgcn_sched_barrier(0);                \
  } while (0)
#define WAITLGKM()                                    \
  do {                                                \
    __builtin_amdgcn_sched_barrier(0);                \
    __builtin_amdgcn_s_waitcnt(0xC07F);               \
    __builtin_amdgcn_sched_barrier(0);                \
  } while (0)

// ---------------------------------------------------------------------------
// prep_xF: X [4096][512] fp32 -> A-frag-major bf16 (unchanged from r8).
// ---------------------------------------------------------------------------
__global__ __launch_bounds__(256) void prep_xF(const float* __restrict__ X,
                                               unsigned short* __restrict__ XbF) {
  const int w = threadIdx.x >> 6, lane = threadIdx.x & 63;
  const int r = blockIdx.x * 4 + w;
  const float* src = X + (size_t)r * DM + lane * 8;
  float4 a = *(const float4*)src;
  float4 b = *(const float4*)(src + 4);
  ushort4 o0, o1;
  o0.x = f2bf(a.x); o0.y = f2bf(a.y); o0.z = f2bf(a.z); o0.w = f2bf(a.w);
  o1.x = f2bf(b.x); o1.y = f2bf(b.y); o1.z = f2bf(b.z); o1.w = f2bf(b.w);
  const int mc = r >> 4, kf = lane >> 2, l = (lane & 3) * 16 + (r & 15);
  size_t flat = (((size_t)mc * 16 + kf) * 64 + l) * 8;
  *(ushort4*)(XbF + flat) = o0;
  *(ushort4*)(XbF + flat + 4) = o1;
}

// ---------------------------------------------------------------------------
// prep_wF: W -> B-frag-major bf16 (unchanged from r8). z=3 Wo hi, z=4 Wo lo.
// ---------------------------------------------------------------------------
__global__ __launch_bounds__(256) void prep_wF(const float* __restrict__ Wq,
                                               const float* __restrict__ Wk,
                                               const float* __restrict__ Wv,
                                               const float* __restrict__ Wo,
                                               unsigned short* __restrict__ WqF,
                                               unsigned short* __restrict__ WkF,
                                               unsigned short* __restrict__ WvF,
                                               unsigned short* __restrict__ WoFh,
                                               unsigned short* __restrict__ WoFl) {
  const int z = blockIdx.z;
  const float* src = z == 0 ? Wq : z == 1 ? Wk : z == 2 ? Wv : Wo;
  unsigned short* dst = z == 0 ? WqF : z == 1 ? WkF : z == 2 ? WvF : z == 3 ? WoFh : WoFl;
  const int k0 = blockIdx.y * 32, n0 = blockIdx.x * 32;
  __shared__ float t[32][33];
  const int tid = threadIdx.x;
#pragma unroll
  for (int u = 0; u < 4; ++u) {
    int idx = u * 256 + tid, r = idx >> 5, c = idx & 31;
    t[r][c] = src[(size_t)(k0 + r) * DM + n0 + c];
  }
  __syncthreads();
  const int ncl = tid >> 7, l = (tid >> 1) & 63, eh = tid & 1;
  const int nl = ncl * 16 + (l & 15);
  const int klb = (l >> 4) * 8 + eh * 4;
  ushort4 o;
  {
    float v0 = t[klb + 0][nl], v1 = t[klb + 1][nl], v2 = t[klb + 2][nl], v3 = t[klb + 3][nl];
    unsigned short h0 = f2bf(v0), h1 = f2bf(v1), h2 = f2bf(v2), h3 = f2bf(v3);
    if (z == 4) {
      h0 = f2bf(v0 - bf2f(h0)); h1 = f2bf(v1 - bf2f(h1));
      h2 = f2bf(v2 - bf2f(h2)); h3 = f2bf(v3 - bf2f(h3));
    }
    o.x = h0; o.y = h1; o.z = h2; o.w = h3;
  }
  size_t flat = (((size_t)((n0 >> 4) + ncl) * 16 + (k0 >> 5)) * 64 + l) * 8 + eh * 4;
  *(ushort4*)(dst + flat) = o;
}

// ---------------------------------------------------------------------------
// pk_trans: Pk [1023][8] fp32 -> Pkt [8][1040] fp32 (unit-stride rows, 0-pad).
// ---------------------------------------------------------------------------
__global__ __launch_bounds__(256) void pk_trans(const float* __restrict__ Pk,
                                                float* __restrict__ Pkt) {
  const int h = blockIdx.y;
  const int g = blockIdx.x * 256 + threadIdx.x;
  if (g < 1040)
    Pkt[(size_t)h * 1040 + g] = (g < NUMREL) ? Pk[(size_t)g * Hh + h] : 0.f;
}

// ---------------------------------------------------------------------------
// pv_fragprep: Pv [1023][8][64] fp32 -> PvF2 [a(2)][h][dt(4)][gt(32)][l(64)][e(8)]
// bf16. Chunk (a,h,dt,gt) element [l][e] = Pv[g = a*16+gt*32+(l>>4)*8+e][h][dt*16+(l&15)],
// zero for g >= 1023. Both 32-alignment phases stored. grid (16, 8).
// ---------------------------------------------------------------------------
__global__ __launch_bounds__(256) void pv_fragprep(const float* __restrict__ Pv,
                                                   unsigned short* __restrict__ PvF2) {
  const int g0 = blockIdx.x * 64, h = blockIdx.y;
  __shared__ float t[80][64];
  const int tid = threadIdx.x;
#pragma unroll
  for (int u = 0; u < 20; ++u) {
    int idx = u * 256 + tid, r = idx >> 6, c = idx & 63;
    int g = g0 + r;
    t[r][c] = (g < NUMREL) ? Pv[(size_t)g * 512 + h * 64 + c] : 0.f;
  }
  __syncthreads();
#pragma unroll
  for (int av = 0; av < 2; ++av)
#pragma unroll
    for (int gtl = 0; gtl < 2; ++gtl) {
      int gt = (g0 >> 5) + gtl;
#pragma unroll
      for (int dt = 0; dt < 4; ++dt) {
        size_t base = ((((size_t)av * Hh + h) * 4 + dt) * 32 + gt) * 512;
        int idx = tid * 2;
        int l = idx >> 3, e = idx & 7;
        int gr = av * 16 + gtl * 32 + (l >> 4) * 8 + e;   // e, e+1 share l
        int dcol = dt * 16 + (l & 15);
        ushort2 o;
        o.x = f2bf(t[gr][dcol]);
        o.y = f2bf(t[gr + 1][dcol]);
        *(ushort2*)(PvF2 + base + idx) = o;
      }
    }
}

// ---------------------------------------------------------------------------
// gemm_qkv: z-fused frag-major staged GEMM (r8 structure). Epilogue now emits
// Qb row-major, KF frag-major [bh][jt][kf][l][e], VF frag-major [bh][dt][ks][l][e].
// ---------------------------------------------------------------------------
__global__ __launch_bounds__(256, 2) void gemm_qkv(const unsigned short* __restrict__ XbF,
                                                   const unsigned short* __restrict__ WqF,
                                                   const unsigned short* __restrict__ WkF,
                                                   const unsigned short* __restrict__ WvF,
                                                   const float* __restrict__ bq,
                                                   const float* __restrict__ bk,
                                                   const float* __restrict__ bv,
                                                   unsigned short* __restrict__ Qb,
                                                   unsigned short* __restrict__ KF,
                                                   unsigned short* __restrict__ VF) {
  const int flat = blockIdx.x;
  const int xcd = flat & 7, g = flat >> 3;
  const int by = xcd * 8 + (g & 7), bx = g >> 3;
  const int bm = by * 64, bn = bx * 64;
  const int mc0 = bm >> 4, nc0 = bn >> 4;
  const int tid = threadIdx.x, w = tid >> 6, lane = tid & 63;
  const int lo = lane & 15, quad = lane >> 4;
  const int mh = (w >> 1) * 2, nh = (w & 1) * 2;

  __shared__ __align__(16) unsigned short stg[2][16 * 512];

  const unsigned short* srcArr = w == 0 ? XbF : w == 1 ? WqF : w == 2 ? WkF : WvF;
  const int rowbase = (w == 0) ? mc0 : nc0;

#define STAGE(buf, kf)                                                          \
  do {                                                                          \
    _Pragma("unroll") for (int t = 0; t < 4; ++t) {                             \
      gl_lds16(srcArr + (((size_t)(rowbase + t) * 16 + (kf)) * 512) + lane * 8, \
               &stg[buf][(w * 4 + t) * 512]);                                   \
    }                                                                           \
  } while (0)

  f32x4 acc[3][2][2] = {};
  STAGE(0, 0);
  int cur = 0;
#pragma unroll
  for (int kf = 0; kf < 16; ++kf) {
    __syncthreads();
    if (kf < 15) STAGE(cur ^ 1, kf + 1);
    bf16x8 af[2], bq_[2], bk_[2], bv_[2];
#pragma unroll
    for (int i = 0; i < 2; ++i)
      af[i] = *(const bf16x8*)(&stg[cur][(mh + i) * 512 + lane * 8]);
#pragma unroll
    for (int j = 0; j < 2; ++j) {
      bq_[j] = *(const bf16x8*)(&stg[cur][(4 + nh + j) * 512 + lane * 8]);
      bk_[j] = *(const bf16x8*)(&stg[cur][(8 + nh + j) * 512 + lane * 8]);
      bv_[j] = *(const bf16x8*)(&stg[cur][(12 + nh + j) * 512 + lane * 8]);
    }
#pragma unroll
    for (int i = 0; i < 2; ++i)
#pragma unroll
      for (int j = 0; j < 2; ++j) {
        acc[0][i][j] = __builtin_amdgcn_mfma_f32_16x16x32_bf16(af[i], bq_[j], acc[0][i][j], 0, 0, 0);
        acc[1][i][j] = __builtin_amdgcn_mfma_f32_16x16x32_bf16(af[i], bk_[j], acc[1][i][j], 0, 0, 0);
        acc[2][i][j] = __builtin_amdgcn_mfma_f32_16x16x32_bf16(af[i], bv_[j], acc[2][i][j], 0, 0, 0);
      }
    cur ^= 1;
  }
#undef STAGE

  const int mt = (w >> 1) * 32, nt = (w & 1) * 32;
#pragma unroll
  for (int z = 0; z < 3; ++z) {
    const float* bias = z == 0 ? bq : z == 1 ? bk : bv;
#pragma unroll
    for (int i = 0; i < 2; ++i)
#pragma unroll
      for (int j = 0; j < 2; ++j) {
        int col = bn + nt + j * 16 + lo;
        int h = col >> 6, d = col & 63;
        float bb = bias[col];
#pragma unroll
        for (int r = 0; r < 4; ++r) {
          int row = bm + mt + i * 16 + quad * 4 + r;
          int b = row >> 9, is = row & 511;
          int bh = b * Hh + h;
          unsigned short val = f2bf(acc[z][i][j][r] + bb);
          if (z == 0) {
            Qb[((size_t)bh * Nseq + is) * 64 + d] = val;
          } else if (z == 1) {
            int jt = is >> 4, kf2 = d >> 5, l = ((d >> 3) & 3) * 16 + (is & 15), e = d & 7;
            KF[(((size_t)bh * 32 + jt) * 2 + kf2) * 512 + l * 8 + e] = val;
          } else {
            int dt = d >> 4, ks = is >> 5, l = ((is >> 3) & 3) * 16 + (d & 15), e = is & 7;
            VF[(((size_t)bh * 4 + dt) * 16 + ks) * 512 + l * 8 + e] = val;
          }
        }
      }
  }
}

// ---------------------------------------------------------------------------
// attn_fused: 13-granule per-wave global_load_lds pipeline.
// Granules (16 KB, 4 chunks/wave): K0..K3, V0..V3, Pv0..Pv4 (last = 1 chunk).
// Per-wave staging/reads -> no barriers in staging loops, only manual vmcnt.
// P' (shifted) fragments = unaligned reads of apron-padded pstrip (no pshift).
// ---------------------------------------------------------------------------
__global__ __launch_bounds__(256, 3) void attn_fused(
    const unsigned short* __restrict__ Qb,
    const unsigned short* __restrict__ KF,
    const unsigned short* __restrict__ VF,
    const float* __restrict__ Pkt,
    const unsigned short* __restrict__ PvF2,
    unsigned short* __restrict__ AwFh,
    unsigned short* __restrict__ AwFl) {
  const int flat = blockIdx.x;
  const int xcd = flat & 7;
  const int grp = flat >> 3;
  const int i0 = (grp & 31) * 16;
  const int bh = (grp >> 5) * 8 + xcd;  // h == xcd: Pv/K/V pinned per-XCD L2
  const int b = bh >> 3, h = bh & 7;
  const int tid = threadIdx.x, w = tid >> 6, lane = tid & 63;
  const int lo = lane & 15, quad = lane >> 4;

  __shared__ __align__(16) unsigned short stg[2][16 * 512];  // 2 x 16 KB ping-pong
  __shared__ __align__(16) unsigned short pstrip[16 * STR];  // apron-padded P
  __shared__ float pk_lds[544];
  __shared__ float redm[4][16];
  __shared__ float redl[4][16];

  const int T = ZOFF - i0 - 15;  // 496 - i0, multiple of 16, >= 0

  // zero pstrip (aprons must be 0)
  int4 z4; z4.x = z4.y = z4.z = z4.w = 0;
  for (int c = tid; c < 16 * STR / 8; c += 256) ((int4*)pstrip)[c] = z4;
  // pk_lds <- Pkt[h][T .. T+528) coalesced
  for (int c = tid; c < 132; c += 256)
    *(float4*)(pk_lds + c * 4) = *(const float4*)(Pkt + (size_t)h * 1040 + T + c * 4);

  // Q fragments (2 direct loads; retire under entry barrier)
  const unsigned short* qbase = Qb + ((size_t)bh * Nseq + i0 + lo) * 64;
  bf16x8 qa0 = *(const bf16x8*)(qbase + quad * 8);
  bf16x8 qa1 = *(const bf16x8*)(qbase + 32 + quad * 8);

  const unsigned short* KFb = KF + (size_t)bh * 64 * 512;
  const unsigned short* VFb = VF + ((size_t)bh * 4 + w) * 16 * 512;
  const int aV = (T >> 4) & 1, gt0 = T >> 5;
  const unsigned short* PFb = PvF2 + ((((size_t)aV * Hh + h) * 4 + w) * 32 + gt0) * 512;

#define KSTAGE(g, buf)                                                        \
  do {                                                                        \
    _Pragma("unroll") for (int c = 0; c < 4; ++c) {                           \
      int s_ = 2 * (g) + (c >> 1), kf_ = c & 1, jt_ = w * 8 + s_;             \
      gl_lds16(KFb + ((size_t)jt_ * 2 + kf_) * 512 + lane * 8,                \
               &stg[buf][(w * 4 + c) * 512]);                                 \
    }                                                                         \
  } while (0)
#define VSTAGE(g, buf)                                                        \
  do {                                                                        \
    _Pragma("unroll") for (int c = 0; c < 4; ++c) {                           \
      gl_lds16(VFb + ((size_t)(4 * (g) + c)) * 512 + lane * 8,                \
               &stg[buf][(w * 4 + c) * 512]);                                 \
    }                                                                         \
  } while (0)
#define PSTAGE(g, buf, n)                                                     \
  do {                                                                        \
    _Pragma("unroll") for (int c = 0; c < (n); ++c) {                         \
      gl_lds16(PFb + ((size_t)(4 * (g) + c)) * 512 + lane * 8,                \
               &stg[buf][(w * 4 + c) * 512]);                                 \
    }                                                                         \
  } while (0)

  // stage K granules 0,1; entry barrier drains them + pk/zero writes
  KSTAGE(0, 0);
  KSTAGE(1, 1);
  __builtin_amdgcn_sched_barrier(0);
  __syncthreads();

  // ---------------- Phase 1: scores (K granule pipeline) ----------------
  float sv[8][4];
  float mrow[4] = {-1e30f, -1e30f, -1e30f, -1e30f};
#pragma unroll
  for (int g = 0; g < 4; ++g) {
    if (g >= 2) WAITVM(4);  // granule g landed (g+1 still in flight)
    bf16x8 k00 = *(const bf16x8*)(&stg[g & 1][(w * 4 + 0) * 512 + lane * 8]);
    bf16x8 k01 = *(const bf16x8*)(&stg[g & 1][(w * 4 + 1) * 512 + lane * 8]);
    bf16x8 k10 = *(const bf16x8*)(&stg[g & 1][(w * 4 + 2) * 512 + lane * 8]);
    bf16x8 k11 = *(const bf16x8*)(&stg[g & 1][(w * 4 + 3) * 512 + lane * 8]);
    WAITLGKM();  // fragments in regs; buffer reusable
    if (g == 0) KSTAGE(2, 0);
    else if (g == 1) KSTAGE(3, 1);
    else if (g == 2) VSTAGE(0, 0);
    else VSTAGE(1, 1);
    __builtin_amdgcn_sched_barrier(0);
#pragma unroll
    for (int u = 0; u < 2; ++u) {
      int s = 2 * g + u;
      f32x4 c = {0.f, 0.f, 0.f, 0.f};
      c = __builtin_amdgcn_mfma_f32_16x16x32_bf16(qa0, u ? k10 : k00, c, 0, 0, 0);
      c = __builtin_amdgcn_mfma_f32_16x16x32_bf16(qa1, u ? k11 : k01, c, 0, 0, 0);
      int j = w * 128 + s * 16 + lo;
#pragma unroll
      for (int r = 0; r < 4; ++r) {
        int rl = quad * 4 + r;
        float v = (c[r] + pk_lds[j - rl + 15]) * 0.125f;
        sv[s][r] = v;
        mrow[r] = fmaxf(mrow[r], v);
      }
    }
  }

  // ---------------- softmax ----------------
#pragma unroll
  for (int m = 1; m <= 8; m <<= 1)
#pragma unroll
    for (int r = 0; r < 4; ++r) mrow[r] = fmaxf(mrow[r], __shfl_xor(mrow[r], m));
  if (lo == 0)
#pragma unroll
    for (int r = 0; r < 4; ++r) redm[w][quad * 4 + r] = mrow[r];
  __syncthreads();
  float mfin[4];
#pragma unroll
  for (int r = 0; r < 4; ++r) {
    int rl = quad * 4 + r;
    mfin[r] = fmaxf(fmaxf(redm[0][rl], redm[1][rl]), fmaxf(redm[2][rl], redm[3][rl]));
  }
  float lrow[4] = {0.f, 0.f, 0.f, 0.f};
#pragma unroll
  for (int s = 0; s < 8; ++s)
#pragma unroll
    for (int r = 0; r < 4; ++r) {
      float e = __expf(sv[s][r] - mfin[r]);
      sv[s][r] = e;
      lrow[r] += e;
    }
#pragma unroll
  for (int m = 1; m <= 8; m <<= 1)
#pragma unroll
    for (int r = 0; r < 4; ++r) lrow[r] += __shfl_xor(lrow[r], m);
  if (lo == 0)
#pragma unroll
    for (int r = 0; r < 4; ++r) redl[w][quad * 4 + r] = lrow[r];
  __syncthreads();
#pragma unroll
  for (int r = 0; r < 4; ++r) {
    int rl = quad * 4 + r;
    float linv = 1.f / (redl[0][rl] + redl[1][rl] + redl[2][rl] + redl[3][rl]);
#pragma unroll
    for (int s = 0; s < 8; ++s) {
      int j = w * 128 + s * 16 + lo;
      pstrip[rl * STR + 16 + j] = f2bf(sv[s][r] * linv);
    }
  }
  __syncthreads();

  // ---------------- Phase 2: P@V (V granule pipeline) ----------------
  f32x4 oacc = {0.f, 0.f, 0.f, 0.f};
#pragma unroll
  for (int g = 0; g < 4; ++g) {
    if (g >= 2) WAITVM(4);
    bf16x8 vb[4];
#pragma unroll
    for (int c = 0; c < 4; ++c)
      vb[c] = *(const bf16x8*)(&stg[g & 1][(w * 4 + c) * 512 + lane * 8]);
    WAITLGKM();
    if (g == 0) VSTAGE(2, 0);
    else if (g == 1) VSTAGE(3, 1);
    else if (g == 2) PSTAGE(0, 0, 4);
    else PSTAGE(1, 1, 4);
    __builtin_amdgcn_sched_barrier(0);
#pragma unroll
    for (int c = 0; c < 4; ++c) {
      int ks = 4 * g + c;
      bf16x8 pa = *(const bf16x8*)(&pstrip[lo * STR + 16 + ks * 32 + quad * 8]);
      oacc = __builtin_amdgcn_mfma_f32_16x16x32_bf16(pa, vb[c], oacc, 0, 0, 0);
    }
  }

  // ---------------- Phase 2b: P'@Pv (Pv granule pipeline) ----------------
#pragma unroll
  for (int g = 0; g < 5; ++g) {
    if (g <= 2) WAITVM(4);
    else if (g == 3) WAITVM(1);
    else WAITVM(0);
    const int nc = (g == 4) ? 1 : 4;
    bf16x8 pv[4];
#pragma unroll
    for (int c = 0; c < 4; ++c)
      if (c < nc)
        pv[c] = *(const bf16x8*)(&stg[g & 1][(w * 4 + c) * 512 + lane * 8]);
    WAITLGKM();
    if (g == 0) PSTAGE(2, 0, 4);
    else if (g == 1) PSTAGE(3, 1, 4);
    else if (g == 2) PSTAGE(4, 0, 1);
    __builtin_amdgcn_sched_barrier(0);
#pragma unroll
    for (int c = 0; c < 4; ++c)
      if (c < nc) {
        int ks = 4 * g + c;
        // P'[lo][t] = P[lo][t+lo-15] -> pstrip idx = lo*STR + ks*32+quad*8 + lo + 1
        union { bf16x8 v; short s8[8]; } pa;
        int base = lo * STR + ks * 32 + quad * 8 + lo + 1;
#pragma unroll
        for (int e = 0; e < 8; ++e) pa.s8[e] = (short)pstrip[base + e];
        oacc = __builtin_amdgcn_mfma_f32_16x16x32_bf16(pa.v, pv[c], oacc, 0, 0, 0);
      }
  }

  // epilogue: A-frag-major AwF hi/lo; row = b*512+i, col = h*64 + (w*16+lo)
  const int mc = b * 32 + (i0 >> 4);
  const int kf = h * 2 + (w >> 1);
  const int lhi = ((w & 1) * 2 + (lo >> 3)) * 16;
#pragma unroll
  for (int r = 0; r < 4; ++r) {
    float o = oacc[r];
    unsigned short hi = f2bf(o);
    unsigned short lov = f2bf(o - bf2f(hi));
    size_t fl = (((size_t)mc * 16 + kf) * 64 + lhi + quad * 4 + r) * 8 + (lo & 7);
    AwFh[fl] = hi;
    AwFl[fl] = lov;
  }
#undef KSTAGE
#undef VSTAGE
#undef PSTAGE
}

// ---------------------------------------------------------------------------
// gemm_final: split-bf16 3-term staged GEMM (unchanged from r8).
// ---------------------------------------------------------------------------
__global__ __launch_bounds__(256, 2) void gemm_final(const unsigned short* __restrict__ AhF,
                                                     const unsigned short* __restrict__ AlF,
                                                     const unsigned short* __restrict__ BhF,
                                                     const unsigned short* __restrict__ BlF,
                                                     const float* __restrict__ bo,
                                                     float* __restrict__ out) {
  const int flat = blockIdx.x;
  const int xcd = flat & 7, g = flat >> 3;
  const int by = xcd * 8 + (g & 7), bx = g >> 3;
  const int bm = by * 64, bn = bx * 64;
  const int mc0 = bm >> 4, nc0 = bn >> 4;
  const int tid = threadIdx.x, w = tid >> 6, lane = tid & 63;
  const int lo = lane & 15, quad = lane >> 4;
  const int mh = (w >> 1) * 2, nh = (w & 1) * 2;

  __shared__ __align__(16) unsigned short stg[2][16 * 512];

  const unsigned short* srcArr = w == 0 ? AhF : w == 1 ? AlF : w == 2 ? BhF : BlF;
  const int rowbase = (w < 2) ? mc0 : nc0;

#define STAGE2(buf, kf)                                                         \
  do {                                                                          \
    _Pragma("unroll") for (int t = 0; t < 4; ++t) {                             \
      gl_lds16(srcArr + (((size_t)(rowbase + t) * 16 + (kf)) * 512) + lane * 8, \
               &stg[buf][(w * 4 + t) * 512]);                                   \
    }                                                                           \
  } while (0)

  f32x4 acc[2][2] = {};
  STAGE2(0, 0);
  int cur = 0;
#pragma unroll
  for (int kf = 0; kf < 16; ++kf) {
    __syncthreads();
    if (kf < 15) STAGE2(cur ^ 1, kf + 1);
    bf16x8 ah[2], al[2], bh[2], bl[2];
#pragma unroll
    for (int i = 0; i < 2; ++i) {
      ah[i] = *(const bf16x8*)(&stg[cur][(mh + i) * 512 + lane * 8]);
      al[i] = *(const bf16x8*)(&stg[cur][(4 + mh + i) * 512 + lane * 8]);
    }
#pragma unroll
    for (int j = 0; j < 2; ++j) {
      bh[j] = *(const bf16x8*)(&stg[cur][(8 + nh + j) * 512 + lane * 8]);
      bl[j] = *(const bf16x8*)(&stg[cur][(12 + nh + j) * 512 + lane * 8]);
    }
#pragma unroll
    for (int i = 0; i < 2; ++i)
#pragma unroll
      for (int j = 0; j < 2; ++j) {
        acc[i][j] = __builtin_amdgcn_mfma_f32_16x16x32_bf16(ah[i], bh[j], acc[i][j], 0, 0, 0);
        acc[i][j] = __builtin_amdgcn_mfma_f32_16x16x32_bf16(ah[i], bl[j], acc[i][j], 0, 0, 0);
        acc[i][j] = __builtin_amdgcn_mfma_f32_16x16x32_bf16(al[i], bh[j], acc[i][j], 0, 0, 0);
      }
    cur ^= 1;
  }
#undef STAGE2

  const int mt = (w >> 1) * 32, nt = (w & 1) * 32;
#pragma unroll
  for (int i = 0; i < 2; ++i)
#pragma unroll
    for (int j = 0; j < 2; ++j) {
      int col = bn + nt + j * 16 + lo;
      float bb = bo[col];
#pragma unroll
      for (int r = 0; r < 4; ++r) {
        int row = bm + mt + i * 16 + quad * 4 + r;
        out[(size_t)row * DM + col] = acc[i][j][r] + bb;
      }
    }
}

// ---------------------------------------------------------------------------
extern "C" void kernel_launch(void* const* d_in, const int* in_sizes, int n_in,
                              void* d_out, int out_size, void* d_ws, size_t ws_size,
                              hipStream_t stream) {
  const float* X  = (const float*)d_in[0];
  const float* Wq = (const float*)d_in[1];
  const float* bq = (const float*)d_in[2];
  const float* Wk = (const float*)d_in[3];
  const float* bk = (const float*)d_in[4];
  const float* Wv = (const float*)d_in[5];
  const float* bv = (const float*)d_in[6];
  const float* Wo = (const float*)d_in[7];
  const float* bo = (const float*)d_in[8];
  const float* Pk = (const float*)d_in[9];
  const float* Pv = (const float*)d_in[10];
  float* out = (float*)d_out;

  char* p = (char*)d_ws;
  const size_t szX    = (size_t)Bc * Nseq * DM * 2;        // 4 MB (frag-major)
  const size_t szW    = (size_t)DM * DM * 2;               // 512 KB
  const size_t szPkt  = (size_t)Hh * 1040 * 4;             // ~32.5 KB
  const size_t szPvF2 = (size_t)2 * Hh * 4 * 32 * 512 * 2; // 2 MB
  const size_t szQKV  = (size_t)Bc * Hh * Nseq * 64 * 2;   // 4 MB
  unsigned short* XbF  = (unsigned short*)p; p += szX;
  unsigned short* WqF  = (unsigned short*)p; p += szW;
  unsigned short* WkF  = (unsigned short*)p; p += szW;
  unsigned short* WvF  = (unsigned short*)p; p += szW;
  unsigned short* WoFh = (unsigned short*)p; p += szW;
  unsigned short* WoFl = (unsigned short*)p; p += szW;
  float*          Pkt  = (float*)p;          p += (szPkt + 255) & ~(size_t)255;
  unsigned short* PvF2 = (unsigned short*)p; p += szPvF2;
  unsigned short* Qb   = (unsigned short*)p; p += szQKV;
  unsigned short* KF   = (unsigned short*)p; p += szQKV;
  unsigned short* VF   = (unsigned short*)p; p += szQKV;
  unsigned short* AwFh = (unsigned short*)p; p += szX;
  unsigned short* AwFl = (unsigned short*)p; p += szX;

  dim3 blk(256);
  prep_xF<<<dim3(1024), blk, 0, stream>>>(X, XbF);
  prep_wF<<<dim3(16, 16, 5), blk, 0, stream>>>(Wq, Wk, Wv, Wo, WqF, WkF, WvF, WoFh, WoFl);
  pk_trans<<<dim3(5, 8), blk, 0, stream>>>(Pk, Pkt);
  pv_fragprep<<<dim3(16, 8), blk, 0, stream>>>(Pv, PvF2);
  gemm_qkv<<<dim3(512), blk, 0, stream>>>(XbF, WqF, WkF, WvF, bq, bk, bv, Qb, KF, VF);
  attn_fused<<<dim3(2048), blk, 0, stream>>>(Qb, KF, VF, Pkt, PvF2, AwFh, AwFl);
  gemm_final<<<dim3(512), blk, 0, stream>>>(AwFh, AwFl, WoFh, WoFl, bo, out);
}

// Round 10
// 151.831 us; speedup vs baseline: 1.2976x; 1.0334x over previous
//
#include <hip/hip_runtime.h>
#include <math.h>

#define Bc 8
#define Nseq 512
#define DM 512
#define Hh 8
#define NUMREL 1023
#define ZOFF 511     // NUMREL/2
#define STR 568      // pstrip row stride (shorts): 16-apron + 512 + tail zeros

typedef short bf16x8 __attribute__((ext_vector_type(8)));
typedef float f32x4 __attribute__((ext_vector_type(4)));

__device__ __forceinline__ unsigned short f2bf(float f) {
  unsigned u = __builtin_bit_cast(unsigned, f);
  u += 0x7fff + ((u >> 16) & 1);  // RNE
  return (unsigned short)(u >> 16);
}
__device__ __forceinline__ float bf2f(unsigned short h) {
  unsigned u = ((unsigned)h) << 16;
  return __builtin_bit_cast(float, u);
}

// async global->LDS, 16 B per lane; LDS dest = wave-uniform base + lane*16.
typedef __attribute__((address_space(3))) unsigned int as3_uint;
typedef __attribute__((address_space(1))) const unsigned int as1_uint;
__device__ __forceinline__ void gl_lds16(const void* g, void* l) {
  __builtin_amdgcn_global_load_lds((as1_uint*)g, (as3_uint*)l, 16, 0, 0);
}

// manual waitcnt helpers (sched_barrier-pinned so nothing floats across)
#define WAITVM(n)                                     \
  do {                                                \
    __builtin_amdgcn_sched_barrier(0);                \
    __builtin_amdgcn_s_waitcnt(0x0F70 | (n));         \
    __builtin_amdgcn_sched_barrier(0);                \
  } while (0)
#define WAITLGKM()                                    \
  do {                                                \
    __builtin_amdgcn_sched_barrier(0);                \
    __builtin_amdgcn_s_waitcnt(0xC07F);               \
    __builtin_amdgcn_sched_barrier(0);                \
  } while (0)

// ---------------------------------------------------------------------------
// prep_xF: X [4096][512] fp32 -> A-frag-major bf16 (unchanged).
// ---------------------------------------------------------------------------
__global__ __launch_bounds__(256) void prep_xF(const float* __restrict__ X,
                                               unsigned short* __restrict__ XbF) {
  const int w = threadIdx.x >> 6, lane = threadIdx.x & 63;
  const int r = blockIdx.x * 4 + w;
  const float* src = X + (size_t)r * DM + lane * 8;
  float4 a = *(const float4*)src;
  float4 b = *(const float4*)(src + 4);
  ushort4 o0, o1;
  o0.x = f2bf(a.x); o0.y = f2bf(a.y); o0.z = f2bf(a.z); o0.w = f2bf(a.w);
  o1.x = f2bf(b.x); o1.y = f2bf(b.y); o1.z = f2bf(b.z); o1.w = f2bf(b.w);
  const int mc = r >> 4, kf = lane >> 2, l = (lane & 3) * 16 + (r & 15);
  size_t flat = (((size_t)mc * 16 + kf) * 64 + l) * 8;
  *(ushort4*)(XbF + flat) = o0;
  *(ushort4*)(XbF + flat + 4) = o1;
}

// ---------------------------------------------------------------------------
// prep_wF: W -> B-frag-major bf16 (unchanged). z=3 Wo hi, z=4 Wo lo.
// ---------------------------------------------------------------------------
__global__ __launch_bounds__(256) void prep_wF(const float* __restrict__ Wq,
                                               const float* __restrict__ Wk,
                                               const float* __restrict__ Wv,
                                               const float* __restrict__ Wo,
                                               unsigned short* __restrict__ WqF,
                                               unsigned short* __restrict__ WkF,
                                               unsigned short* __restrict__ WvF,
                                               unsigned short* __restrict__ WoFh,
                                               unsigned short* __restrict__ WoFl) {
  const int z = blockIdx.z;
  const float* src = z == 0 ? Wq : z == 1 ? Wk : z == 2 ? Wv : Wo;
  unsigned short* dst = z == 0 ? WqF : z == 1 ? WkF : z == 2 ? WvF : z == 3 ? WoFh : WoFl;
  const int k0 = blockIdx.y * 32, n0 = blockIdx.x * 32;
  __shared__ float t[32][33];
  const int tid = threadIdx.x;
#pragma unroll
  for (int u = 0; u < 4; ++u) {
    int idx = u * 256 + tid, r = idx >> 5, c = idx & 31;
    t[r][c] = src[(size_t)(k0 + r) * DM + n0 + c];
  }
  __syncthreads();
  const int ncl = tid >> 7, l = (tid >> 1) & 63, eh = tid & 1;
  const int nl = ncl * 16 + (l & 15);
  const int klb = (l >> 4) * 8 + eh * 4;
  ushort4 o;
  {
    float v0 = t[klb + 0][nl], v1 = t[klb + 1][nl], v2 = t[klb + 2][nl], v3 = t[klb + 3][nl];
    unsigned short h0 = f2bf(v0), h1 = f2bf(v1), h2 = f2bf(v2), h3 = f2bf(v3);
    if (z == 4) {
      h0 = f2bf(v0 - bf2f(h0)); h1 = f2bf(v1 - bf2f(h1));
      h2 = f2bf(v2 - bf2f(h2)); h3 = f2bf(v3 - bf2f(h3));
    }
    o.x = h0; o.y = h1; o.z = h2; o.w = h3;
  }
  size_t flat = (((size_t)((n0 >> 4) + ncl) * 16 + (k0 >> 5)) * 64 + l) * 8 + eh * 4;
  *(ushort4*)(dst + flat) = o;
}

// ---------------------------------------------------------------------------
// pk_trans: Pk [1023][8] fp32 -> Pkt [8][1040] fp32 (unit-stride rows, 0-pad).
// ---------------------------------------------------------------------------
__global__ __launch_bounds__(256) void pk_trans(const float* __restrict__ Pk,
                                                float* __restrict__ Pkt) {
  const int h = blockIdx.y;
  const int g = blockIdx.x * 256 + threadIdx.x;
  if (g < 1040)
    Pkt[(size_t)h * 1040 + g] = (g < NUMREL) ? Pk[(size_t)g * Hh + h] : 0.f;
}

// ---------------------------------------------------------------------------
// pv_fragprep: Pv -> PvF2 [a(2)][h][dt(4)][gt(32)][l(64)][e(8)] bf16 (unchanged).
// ---------------------------------------------------------------------------
__global__ __launch_bounds__(256) void pv_fragprep(const float* __restrict__ Pv,
                                                   unsigned short* __restrict__ PvF2) {
  const int g0 = blockIdx.x * 64, h = blockIdx.y;
  __shared__ float t[80][64];
  const int tid = threadIdx.x;
#pragma unroll
  for (int u = 0; u < 20; ++u) {
    int idx = u * 256 + tid, r = idx >> 6, c = idx & 63;
    int g = g0 + r;
    t[r][c] = (g < NUMREL) ? Pv[(size_t)g * 512 + h * 64 + c] : 0.f;
  }
  __syncthreads();
#pragma unroll
  for (int av = 0; av < 2; ++av)
#pragma unroll
    for (int gtl = 0; gtl < 2; ++gtl) {
      int gt = (g0 >> 5) + gtl;
#pragma unroll
      for (int dt = 0; dt < 4; ++dt) {
        size_t base = ((((size_t)av * Hh + h) * 4 + dt) * 32 + gt) * 512;
        int idx = tid * 2;
        int l = idx >> 3, e = idx & 7;
        int gr = av * 16 + gtl * 32 + (l >> 4) * 8 + e;
        int dcol = dt * 16 + (l & 15);
        ushort2 o;
        o.x = f2bf(t[gr][dcol]);
        o.y = f2bf(t[gr + 1][dcol]);
        *(ushort2*)(PvF2 + base + idx) = o;
      }
    }
}

// ---------------------------------------------------------------------------
// gemm_qkv: z-fused frag-major staged GEMM (unchanged from r9).
// ---------------------------------------------------------------------------
__global__ __launch_bounds__(256, 2) void gemm_qkv(const unsigned short* __restrict__ XbF,
                                                   const unsigned short* __restrict__ WqF,
                                                   const unsigned short* __restrict__ WkF,
                                                   const unsigned short* __restrict__ WvF,
                                                   const float* __restrict__ bq,
                                                   const float* __restrict__ bk,
                                                   const float* __restrict__ bv,
                                                   unsigned short* __restrict__ Qb,
                                                   unsigned short* __restrict__ KF,
                                                   unsigned short* __restrict__ VF) {
  const int flat = blockIdx.x;
  const int xcd = flat & 7, g = flat >> 3;
  const int by = xcd * 8 + (g & 7), bx = g >> 3;
  const int bm = by * 64, bn = bx * 64;
  const int mc0 = bm >> 4, nc0 = bn >> 4;
  const int tid = threadIdx.x, w = tid >> 6, lane = tid & 63;
  const int lo = lane & 15, quad = lane >> 4;
  const int mh = (w >> 1) * 2, nh = (w & 1) * 2;

  __shared__ __align__(16) unsigned short stg[2][16 * 512];

  const unsigned short* srcArr = w == 0 ? XbF : w == 1 ? WqF : w == 2 ? WkF : WvF;
  const int rowbase = (w == 0) ? mc0 : nc0;

#define STAGE(buf, kf)                                                          \
  do {                                                                          \
    _Pragma("unroll") for (int t = 0; t < 4; ++t) {                             \
      gl_lds16(srcArr + (((size_t)(rowbase + t) * 16 + (kf)) * 512) + lane * 8, \
               &stg[buf][(w * 4 + t) * 512]);                                   \
    }                                                                           \
  } while (0)

  f32x4 acc[3][2][2] = {};
  STAGE(0, 0);
  int cur = 0;
#pragma unroll
  for (int kf = 0; kf < 16; ++kf) {
    __syncthreads();
    if (kf < 15) STAGE(cur ^ 1, kf + 1);
    bf16x8 af[2], bq_[2], bk_[2], bv_[2];
#pragma unroll
    for (int i = 0; i < 2; ++i)
      af[i] = *(const bf16x8*)(&stg[cur][(mh + i) * 512 + lane * 8]);
#pragma unroll
    for (int j = 0; j < 2; ++j) {
      bq_[j] = *(const bf16x8*)(&stg[cur][(4 + nh + j) * 512 + lane * 8]);
      bk_[j] = *(const bf16x8*)(&stg[cur][(8 + nh + j) * 512 + lane * 8]);
      bv_[j] = *(const bf16x8*)(&stg[cur][(12 + nh + j) * 512 + lane * 8]);
    }
#pragma unroll
    for (int i = 0; i < 2; ++i)
#pragma unroll
      for (int j = 0; j < 2; ++j) {
        acc[0][i][j] = __builtin_amdgcn_mfma_f32_16x16x32_bf16(af[i], bq_[j], acc[0][i][j], 0, 0, 0);
        acc[1][i][j] = __builtin_amdgcn_mfma_f32_16x16x32_bf16(af[i], bk_[j], acc[1][i][j], 0, 0, 0);
        acc[2][i][j] = __builtin_amdgcn_mfma_f32_16x16x32_bf16(af[i], bv_[j], acc[2][i][j], 0, 0, 0);
      }
    cur ^= 1;
  }
#undef STAGE

  const int mt = (w >> 1) * 32, nt = (w & 1) * 32;
#pragma unroll
  for (int z = 0; z < 3; ++z) {
    const float* bias = z == 0 ? bq : z == 1 ? bk : bv;
#pragma unroll
    for (int i = 0; i < 2; ++i)
#pragma unroll
      for (int j = 0; j < 2; ++j) {
        int col = bn + nt + j * 16 + lo;
        int h = col >> 6, d = col & 63;
        float bb = bias[col];
#pragma unroll
        for (int r = 0; r < 4; ++r) {
          int row = bm + mt + i * 16 + quad * 4 + r;
          int b = row >> 9, is = row & 511;
          int bh = b * Hh + h;
          unsigned short val = f2bf(acc[z][i][j][r] + bb);
          if (z == 0) {
            Qb[((size_t)bh * Nseq + is) * 64 + d] = val;
          } else if (z == 1) {
            int jt = is >> 4, kf2 = d >> 5, l = ((d >> 3) & 3) * 16 + (is & 15), e = d & 7;
            KF[(((size_t)bh * 32 + jt) * 2 + kf2) * 512 + l * 8 + e] = val;
          } else {
            int dt = d >> 4, ks = is >> 5, l = ((is >> 3) & 3) * 16 + (d & 15), e = is & 7;
            VF[(((size_t)bh * 4 + dt) * 16 + ks) * 512 + l * 8 + e] = val;
          }
        }
      }
  }
}

// ---------------------------------------------------------------------------
// attn_fused: TILE-PAIR block {it, it+2} (32 rows, same Pv phase), grid 1024.
// K staged once per block (both tiles), V once, Pv 18-chunk shared window.
// Each staged B-fragment feeds 2 MFMAs. Staging traffic halved vs r9.
// ---------------------------------------------------------------------------
__global__ __launch_bounds__(256, 2) void attn_fused(
    const unsigned short* __restrict__ Qb,
    const unsigned short* __restrict__ KF,
    const unsigned short* __restrict__ VF,
    const float* __restrict__ Pkt,
    const unsigned short* __restrict__ PvF2,
    unsigned short* __restrict__ AwFh,
    unsigned short* __restrict__ AwFl) {
  const int flat = blockIdx.x;
  const int h = flat & 7;            // XCD-pinned
  const int grp = flat >> 3;         // [0,128)
  const int b = grp >> 4;            // [0,8)
  const int p = grp & 15;            // [0,16)
  const int itA = (p >> 1) * 4 + (p & 1);   // pairs {0,2},{1,3},{4,6},{5,7},...
  const int i0A = itA * 16;
  const int i0B = i0A + 32;
  const int bh = b * Hh + h;
  const int tid = threadIdx.x, w = tid >> 6, lane = tid & 63;
  const int lo = lane & 15, quad = lane >> 4;

  __shared__ __align__(16) unsigned short stg[2][16 * 512];  // 32 KB ping-pong
  __shared__ __align__(16) unsigned short pstA[16 * STR];
  __shared__ __align__(16) unsigned short pstB[16 * STR];
  __shared__ float pk_lds[560];
  __shared__ float redm[2][4][16];
  __shared__ float redl[2][4][16];

  const int TB = ZOFF - i0B - 15;  // in [0,464], mult of 16; T_A = TB + 32

  // zero both pstrips (aprons/tails must be 0)
  int4 z4; z4.x = z4.y = z4.z = z4.w = 0;
  for (int c = tid; c < 16 * STR / 8; c += 256) {
    ((int4*)pstA)[c] = z4;
    ((int4*)pstB)[c] = z4;
  }
  // pk band union: [TB, TB+560); tile B offset 0, tile A offset +32
  for (int c = tid; c < 140; c += 256)
    *(float4*)(pk_lds + c * 4) = *(const float4*)(Pkt + (size_t)h * 1040 + TB + c * 4);

  // Q fragments, both tiles (retire under entry barrier)
  const unsigned short* qA = Qb + ((size_t)bh * Nseq + i0A + lo) * 64;
  const unsigned short* qB = Qb + ((size_t)bh * Nseq + i0B + lo) * 64;
  bf16x8 qa0 = *(const bf16x8*)(qA + quad * 8);
  bf16x8 qa1 = *(const bf16x8*)(qA + 32 + quad * 8);
  bf16x8 qb0 = *(const bf16x8*)(qB + quad * 8);
  bf16x8 qb1 = *(const bf16x8*)(qB + 32 + quad * 8);

  const unsigned short* KFb = KF + (size_t)bh * 64 * 512;
  const unsigned short* VFb = VF + ((size_t)bh * 4 + w) * 16 * 512;
  const int aP = (TB >> 4) & 1, gtB = TB >> 5;  // gtB+17 <= 31
  const unsigned short* PFb = PvF2 + ((((size_t)aP * Hh + h) * 4 + w) * 32 + gtB) * 512;

#define KSTAGE(g, buf)                                                        \
  do {                                                                        \
    _Pragma("unroll") for (int c = 0; c < 4; ++c) {                           \
      int s_ = 2 * (g) + (c >> 1), kf_ = c & 1, jt_ = w * 8 + s_;             \
      gl_lds16(KFb + ((size_t)jt_ * 2 + kf_) * 512 + lane * 8,                \
               &stg[buf][(w * 4 + c) * 512]);                                 \
    }                                                                         \
  } while (0)
#define VSTAGE(g, buf)                                                        \
  do {                                                                        \
    _Pragma("unroll") for (int c = 0; c < 4; ++c) {                           \
      gl_lds16(VFb + ((size_t)(4 * (g) + c)) * 512 + lane * 8,                \
               &stg[buf][(w * 4 + c) * 512]);                                 \
    }                                                                         \
  } while (0)
#define PSTAGE(g, buf, n)                                                     \
  do {                                                                        \
    _Pragma("unroll") for (int c = 0; c < (n); ++c) {                         \
      gl_lds16(PFb + ((size_t)(4 * (g) + c)) * 512 + lane * 8,                \
               &stg[buf][(w * 4 + c) * 512]);                                 \
    }                                                                         \
  } while (0)

  KSTAGE(0, 0);
  KSTAGE(1, 1);
  __builtin_amdgcn_sched_barrier(0);
  __syncthreads();  // drains stages + zero/pk writes; Q frags retire too

  // ---------------- Phase 1: scores for BOTH tiles ----------------
  float svA[8][4], svB[8][4];
  float mA[4] = {-1e30f, -1e30f, -1e30f, -1e30f};
  float mB[4] = {-1e30f, -1e30f, -1e30f, -1e30f};
#pragma unroll
  for (int g = 0; g < 4; ++g) {
    if (g >= 2) WAITVM(4);
    bf16x8 k00 = *(const bf16x8*)(&stg[g & 1][(w * 4 + 0) * 512 + lane * 8]);
    bf16x8 k01 = *(const bf16x8*)(&stg[g & 1][(w * 4 + 1) * 512 + lane * 8]);
    bf16x8 k10 = *(const bf16x8*)(&stg[g & 1][(w * 4 + 2) * 512 + lane * 8]);
    bf16x8 k11 = *(const bf16x8*)(&stg[g & 1][(w * 4 + 3) * 512 + lane * 8]);
    WAITLGKM();
    if (g == 0) KSTAGE(2, 0);
    else if (g == 1) KSTAGE(3, 1);
    else if (g == 2) VSTAGE(0, 0);
    else VSTAGE(1, 1);
    __builtin_amdgcn_sched_barrier(0);
#pragma unroll
    for (int u = 0; u < 2; ++u) {
      int s = 2 * g + u;
      f32x4 cA = {0.f, 0.f, 0.f, 0.f};
      f32x4 cB = {0.f, 0.f, 0.f, 0.f};
      cA = __builtin_amdgcn_mfma_f32_16x16x32_bf16(qa0, u ? k10 : k00, cA, 0, 0, 0);
      cA = __builtin_amdgcn_mfma_f32_16x16x32_bf16(qa1, u ? k11 : k01, cA, 0, 0, 0);
      cB = __builtin_amdgcn_mfma_f32_16x16x32_bf16(qb0, u ? k10 : k00, cB, 0, 0, 0);
      cB = __builtin_amdgcn_mfma_f32_16x16x32_bf16(qb1, u ? k11 : k01, cB, 0, 0, 0);
      int j = w * 128 + s * 16 + lo;
#pragma unroll
      for (int r = 0; r < 4; ++r) {
        int rl = quad * 4 + r;
        int idx = j - rl + 15;
        float vA = (cA[r] + pk_lds[idx + 32]) * 0.125f;
        float vB = (cB[r] + pk_lds[idx]) * 0.125f;
        svA[s][r] = vA; svB[s][r] = vB;
        mA[r] = fmaxf(mA[r], vA);
        mB[r] = fmaxf(mB[r], vB);
      }
    }
  }

  // ---------------- softmax x2 ----------------
#pragma unroll
  for (int m = 1; m <= 8; m <<= 1)
#pragma unroll
    for (int r = 0; r < 4; ++r) {
      mA[r] = fmaxf(mA[r], __shfl_xor(mA[r], m));
      mB[r] = fmaxf(mB[r], __shfl_xor(mB[r], m));
    }
  if (lo == 0)
#pragma unroll
    for (int r = 0; r < 4; ++r) {
      redm[0][w][quad * 4 + r] = mA[r];
      redm[1][w][quad * 4 + r] = mB[r];
    }
  __syncthreads();
  float mfA[4], mfB[4];
#pragma unroll
  for (int r = 0; r < 4; ++r) {
    int rl = quad * 4 + r;
    mfA[r] = fmaxf(fmaxf(redm[0][0][rl], redm[0][1][rl]), fmaxf(redm[0][2][rl], redm[0][3][rl]));
    mfB[r] = fmaxf(fmaxf(redm[1][0][rl], redm[1][1][rl]), fmaxf(redm[1][2][rl], redm[1][3][rl]));
  }
  float lA[4] = {0.f, 0.f, 0.f, 0.f}, lB[4] = {0.f, 0.f, 0.f, 0.f};
#pragma unroll
  for (int s = 0; s < 8; ++s)
#pragma unroll
    for (int r = 0; r < 4; ++r) {
      float eA = __expf(svA[s][r] - mfA[r]);
      float eB = __expf(svB[s][r] - mfB[r]);
      svA[s][r] = eA; svB[s][r] = eB;
      lA[r] += eA; lB[r] += eB;
    }
#pragma unroll
  for (int m = 1; m <= 8; m <<= 1)
#pragma unroll
    for (int r = 0; r < 4; ++r) {
      lA[r] += __shfl_xor(lA[r], m);
      lB[r] += __shfl_xor(lB[r], m);
    }
  if (lo == 0)
#pragma unroll
    for (int r = 0; r < 4; ++r) {
      redl[0][w][quad * 4 + r] = lA[r];
      redl[1][w][quad * 4 + r] = lB[r];
    }
  __syncthreads();
#pragma unroll
  for (int r = 0; r < 4; ++r) {
    int rl = quad * 4 + r;
    float liA = 1.f / (redl[0][0][rl] + redl[0][1][rl] + redl[0][2][rl] + redl[0][3][rl]);
    float liB = 1.f / (redl[1][0][rl] + redl[1][1][rl] + redl[1][2][rl] + redl[1][3][rl]);
#pragma unroll
    for (int s = 0; s < 8; ++s) {
      int j = w * 128 + s * 16 + lo;
      pstA[rl * STR + 16 + j] = f2bf(svA[s][r] * liA);
      pstB[rl * STR + 16 + j] = f2bf(svB[s][r] * liB);
    }
  }
  __syncthreads();

  // ---------------- Phase 2: P@V, both tiles share V fragments ----------
  f32x4 oA = {0.f, 0.f, 0.f, 0.f};
  f32x4 oB = {0.f, 0.f, 0.f, 0.f};
#pragma unroll
  for (int g = 0; g < 4; ++g) {
    if (g >= 2) WAITVM(4);
    bf16x8 vb[4];
#pragma unroll
    for (int c = 0; c < 4; ++c)
      vb[c] = *(const bf16x8*)(&stg[g & 1][(w * 4 + c) * 512 + lane * 8]);
    WAITLGKM();
    if (g == 0) VSTAGE(2, 0);
    else if (g == 1) VSTAGE(3, 1);
    else if (g == 2) PSTAGE(0, 0, 4);
    else PSTAGE(1, 1, 4);
    __builtin_amdgcn_sched_barrier(0);
#pragma unroll
    for (int c = 0; c < 4; ++c) {
      int ks = 4 * g + c;
      bf16x8 pA = *(const bf16x8*)(&pstA[lo * STR + 16 + ks * 32 + quad * 8]);
      bf16x8 pB = *(const bf16x8*)(&pstB[lo * STR + 16 + ks * 32 + quad * 8]);
      oA = __builtin_amdgcn_mfma_f32_16x16x32_bf16(pA, vb[c], oA, 0, 0, 0);
      oB = __builtin_amdgcn_mfma_f32_16x16x32_bf16(pB, vb[c], oB, 0, 0, 0);
    }
  }

  // ---------------- Phase 2b: P'@Pv, 18-chunk shared window --------------
  // chunk cg: tile B ks = cg (cg<17), tile A ks = cg-1 (cg>=1)
#pragma unroll
  for (int gp = 0; gp < 5; ++gp) {
    if (gp < 3) WAITVM(4);
    else if (gp == 3) WAITVM(2);
    else WAITVM(0);
    const int nc = (gp == 4) ? 2 : 4;
    bf16x8 pv[4];
#pragma unroll
    for (int c = 0; c < 4; ++c)
      if (c < nc)
        pv[c] = *(const bf16x8*)(&stg[gp & 1][(w * 4 + c) * 512 + lane * 8]);
    WAITLGKM();
    if (gp == 0) PSTAGE(2, 0, 4);
    else if (gp == 1) PSTAGE(3, 1, 4);
    else if (gp == 2) PSTAGE(4, 0, 2);
    __builtin_amdgcn_sched_barrier(0);
#pragma unroll
    for (int c = 0; c < 4; ++c)
      if (c < nc) {
        int cg = 4 * gp + c;
        if (cg < 17) {
          union { bf16x8 v; short s8[8]; } pa;
          int base = lo * STR + cg * 32 + quad * 8 + lo + 1;
#pragma unroll
          for (int e = 0; e < 8; ++e) pa.s8[e] = (short)pstB[base + e];
          oB = __builtin_amdgcn_mfma_f32_16x16x32_bf16(pa.v, pv[c], oB, 0, 0, 0);
        }
        if (cg >= 1) {
          union { bf16x8 v; short s8[8]; } pa;
          int base = lo * STR + (cg - 1) * 32 + quad * 8 + lo + 1;
#pragma unroll
          for (int e = 0; e < 8; ++e) pa.s8[e] = (short)pstA[base + e];
          oA = __builtin_amdgcn_mfma_f32_16x16x32_bf16(pa.v, pv[c], oA, 0, 0, 0);
        }
      }
  }

  // epilogue x2: A-frag-major AwF hi/lo
  const int kf = h * 2 + (w >> 1);
  const int lhi = ((w & 1) * 2 + (lo >> 3)) * 16;
#pragma unroll
  for (int t = 0; t < 2; ++t) {
    f32x4 o = t ? oB : oA;
    int mc = b * 32 + itA + t * 2;
#pragma unroll
    for (int r = 0; r < 4; ++r) {
      float ov = o[r];
      unsigned short hi = f2bf(ov);
      unsigned short lov = f2bf(ov - bf2f(hi));
      size_t fl = (((size_t)mc * 16 + kf) * 64 + lhi + quad * 4 + r) * 8 + (lo & 7);
      AwFh[fl] = hi;
      AwFl[fl] = lov;
    }
  }
#undef KSTAGE
#undef VSTAGE
#undef PSTAGE
}

// ---------------------------------------------------------------------------
// gemm_final: split-bf16 3-term staged GEMM (unchanged).
// ---------------------------------------------------------------------------
__global__ __launch_bounds__(256, 2) void gemm_final(const unsigned short* __restrict__ AhF,
                                                     const unsigned short* __restrict__ AlF,
                                                     const unsigned short* __restrict__ BhF,
                                                     const unsigned short* __restrict__ BlF,
                                                     const float* __restrict__ bo,
                                                     float* __restrict__ out) {
  const int flat = blockIdx.x;
  const int xcd = flat & 7, g = flat >> 3;
  const int by = xcd * 8 + (g & 7), bx = g >> 3;
  const int bm = by * 64, bn = bx * 64;
  const int mc0 = bm >> 4, nc0 = bn >> 4;
  const int tid = threadIdx.x, w = tid >> 6, lane = tid & 63;
  const int lo = lane & 15, quad = lane >> 4;
  const int mh = (w >> 1) * 2, nh = (w & 1) * 2;

  __shared__ __align__(16) unsigned short stg[2][16 * 512];

  const unsigned short* srcArr = w == 0 ? AhF : w == 1 ? AlF : w == 2 ? BhF : BlF;
  const int rowbase = (w < 2) ? mc0 : nc0;

#define STAGE2(buf, kf)                                                         \
  do {                                                                          \
    _Pragma("unroll") for (int t = 0; t < 4; ++t) {                             \
      gl_lds16(srcArr + (((size_t)(rowbase + t) * 16 + (kf)) * 512) + lane * 8, \
               &stg[buf][(w * 4 + t) * 512]);                                   \
    }                                                                           \
  } while (0)

  f32x4 acc[2][2] = {};
  STAGE2(0, 0);
  int cur = 0;
#pragma unroll
  for (int kf = 0; kf < 16; ++kf) {
    __syncthreads();
    if (kf < 15) STAGE2(cur ^ 1, kf + 1);
    bf16x8 ah[2], al[2], bh[2], bl[2];
#pragma unroll
    for (int i = 0; i < 2; ++i) {
      ah[i] = *(const bf16x8*)(&stg[cur][(mh + i) * 512 + lane * 8]);
      al[i] = *(const bf16x8*)(&stg[cur][(4 + mh + i) * 512 + lane * 8]);
    }
#pragma unroll
    for (int j = 0; j < 2; ++j) {
      bh[j] = *(const bf16x8*)(&stg[cur][(8 + nh + j) * 512 + lane * 8]);
      bl[j] = *(const bf16x8*)(&stg[cur][(12 + nh + j) * 512 + lane * 8]);
    }
#pragma unroll
    for (int i = 0; i < 2; ++i)
#pragma unroll
      for (int j = 0; j < 2; ++j) {
        acc[i][j] = __builtin_amdgcn_mfma_f32_16x16x32_bf16(ah[i], bh[j], acc[i][j], 0, 0, 0);
        acc[i][j] = __builtin_amdgcn_mfma_f32_16x16x32_bf16(ah[i], bl[j], acc[i][j], 0, 0, 0);
        acc[i][j] = __builtin_amdgcn_mfma_f32_16x16x32_bf16(al[i], bh[j], acc[i][j], 0, 0, 0);
      }
    cur ^= 1;
  }
#undef STAGE2

  const int mt = (w >> 1) * 32, nt = (w & 1) * 32;
#pragma unroll
  for (int i = 0; i < 2; ++i)
#pragma unroll
    for (int j = 0; j < 2; ++j) {
      int col = bn + nt + j * 16 + lo;
      float bb = bo[col];
#pragma unroll
      for (int r = 0; r < 4; ++r) {
        int row = bm + mt + i * 16 + quad * 4 + r;
        out[(size_t)row * DM + col] = acc[i][j][r] + bb;
      }
    }
}

// ---------------------------------------------------------------------------
extern "C" void kernel_launch(void* const* d_in, const int* in_sizes, int n_in,
                              void* d_out, int out_size, void* d_ws, size_t ws_size,
                              hipStream_t stream) {
  const float* X  = (const float*)d_in[0];
  const float* Wq = (const float*)d_in[1];
  const float* bq = (const float*)d_in[2];
  const float* Wk = (const float*)d_in[3];
  const float* bk = (const float*)d_in[4];
  const float* Wv = (const float*)d_in[5];
  const float* bv = (const float*)d_in[6];
  const float* Wo = (const float*)d_in[7];
  const float* bo = (const float*)d_in[8];
  const float* Pk = (const float*)d_in[9];
  const float* Pv = (const float*)d_in[10];
  float* out = (float*)d_out;

  char* p = (char*)d_ws;
  const size_t szX    = (size_t)Bc * Nseq * DM * 2;        // 4 MB (frag-major)
  const size_t szW    = (size_t)DM * DM * 2;               // 512 KB
  const size_t szPkt  = (size_t)Hh * 1040 * 4;             // ~32.5 KB
  const size_t szPvF2 = (size_t)2 * Hh * 4 * 32 * 512 * 2; // 2 MB
  const size_t szQKV  = (size_t)Bc * Hh * Nseq * 64 * 2;   // 4 MB
  unsigned short* XbF  = (unsigned short*)p; p += szX;
  unsigned short* WqF  = (unsigned short*)p; p += szW;
  unsigned short* WkF  = (unsigned short*)p; p += szW;
  unsigned short* WvF  = (unsigned short*)p; p += szW;
  unsigned short* WoFh = (unsigned short*)p; p += szW;
  unsigned short* WoFl = (unsigned short*)p; p += szW;
  float*          Pkt  = (float*)p;          p += (szPkt + 255) & ~(size_t)255;
  unsigned short* PvF2 = (unsigned short*)p; p += szPvF2;
  unsigned short* Qb   = (unsigned short*)p; p += szQKV;
  unsigned short* KF   = (unsigned short*)p; p += szQKV;
  unsigned short* VF   = (unsigned short*)p; p += szQKV;
  unsigned short* AwFh = (unsigned short*)p; p += szX;
  unsigned short* AwFl = (unsigned short*)p; p += szX;

  dim3 blk(256);
  prep_xF<<<dim3(1024), blk, 0, stream>>>(X, XbF);
  prep_wF<<<dim3(16, 16, 5), blk, 0, stream>>>(Wq, Wk, Wv, Wo, WqF, WkF, WvF, WoFh, WoFl);
  pk_trans<<<dim3(5, 8), blk, 0, stream>>>(Pk, Pkt);
  pv_fragprep<<<dim3(16, 8), blk, 0, stream>>>(Pv, PvF2);
  gemm_qkv<<<dim3(512), blk, 0, stream>>>(XbF, WqF, WkF, WvF, bq, bk, bv, Qb, KF, VF);
  attn_fused<<<dim3(1024), blk, 0, stream>>>(Qb, KF, VF, Pkt, PvF2, AwFh, AwFl);
  gemm_final<<<dim3(512), blk, 0, stream>>>(AwFh, AwFl, WoFh, WoFl, bo, out);
}

// Round 11
// 147.150 us; speedup vs baseline: 1.3389x; 1.0318x over previous
//
#include <hip/hip_runtime.h>
#include <math.h>

#define Bc 8
#define Nseq 512
#define DM 512
#define Hh 8
#define NUMREL 1023
#define ZOFF 511   // NUMREL/2
#define STR 552    // pstrip row stride (shorts); row extent used: 544

typedef short bf16x8 __attribute__((ext_vector_type(8)));
typedef float f32x4 __attribute__((ext_vector_type(4)));

__device__ __forceinline__ unsigned short f2bf(float f) {
  unsigned u = __builtin_bit_cast(unsigned, f);
  u += 0x7fff + ((u >> 16) & 1);  // RNE
  return (unsigned short)(u >> 16);
}
__device__ __forceinline__ float bf2f(unsigned short h) {
  unsigned u = ((unsigned)h) << 16;
  return __builtin_bit_cast(float, u);
}

typedef __attribute__((address_space(3))) unsigned int as3_uint;
typedef __attribute__((address_space(1))) const unsigned int as1_uint;
__device__ __forceinline__ void gl_lds16(const void* g, void* l) {
  __builtin_amdgcn_global_load_lds((as1_uint*)g, (as3_uint*)l, 16, 0, 0);
}

// ---------------------------------------------------------------------------
// prep_all: fused prep. bid ranges:
//   [0,1024)      X -> XbF (A-frag-major bf16)
//   [1024,2304)   W -> WqF/WkF/WvF/WoFh/WoFl (B-frag-major)
//   [2304,2344)   Pk -> Pkt [8][1040] fp32
//   [2344,2472)   Pv -> PvF2 [a][h][dt][gt][l][e] bf16
// ---------------------------------------------------------------------------
__global__ __launch_bounds__(256) void prep_all(
    const float* __restrict__ X, const float* __restrict__ Wq,
    const float* __restrict__ Wk, const float* __restrict__ Wv,
    const float* __restrict__ Wo, const float* __restrict__ Pk,
    const float* __restrict__ Pv,
    unsigned short* __restrict__ XbF, unsigned short* __restrict__ WqF,
    unsigned short* __restrict__ WkF, unsigned short* __restrict__ WvF,
    unsigned short* __restrict__ WoFh, unsigned short* __restrict__ WoFl,
    float* __restrict__ Pkt, unsigned short* __restrict__ PvF2) {
  __shared__ float tbuf[5120];
  const int bid = blockIdx.x;
  const int tid = threadIdx.x;

  if (bid < 1024) {
    const int w = tid >> 6, lane = tid & 63;
    const int r = bid * 4 + w;
    const float* src = X + (size_t)r * DM + lane * 8;
    float4 a = *(const float4*)src;
    float4 b = *(const float4*)(src + 4);
    ushort4 o0, o1;
    o0.x = f2bf(a.x); o0.y = f2bf(a.y); o0.z = f2bf(a.z); o0.w = f2bf(a.w);
    o1.x = f2bf(b.x); o1.y = f2bf(b.y); o1.z = f2bf(b.z); o1.w = f2bf(b.w);
    const int mc = r >> 4, kf = lane >> 2, l = (lane & 3) * 16 + (r & 15);
    size_t flat = (((size_t)mc * 16 + kf) * 64 + l) * 8;
    *(ushort4*)(XbF + flat) = o0;
    *(ushort4*)(XbF + flat + 4) = o1;
  } else if (bid < 2304) {
    const int idx = bid - 1024;
    const int z = idx >> 8, r256 = idx & 255;
    const int bx = r256 & 15, by = r256 >> 4;
    const float* src = z == 0 ? Wq : z == 1 ? Wk : z == 2 ? Wv : Wo;
    unsigned short* dst = z == 0 ? WqF : z == 1 ? WkF : z == 2 ? WvF : z == 3 ? WoFh : WoFl;
    const int k0 = by * 32, n0 = bx * 32;
#pragma unroll
    for (int u = 0; u < 4; ++u) {
      int i2 = u * 256 + tid, r = i2 >> 5, c = i2 & 31;
      tbuf[r * 33 + c] = src[(size_t)(k0 + r) * DM + n0 + c];
    }
    __syncthreads();
    const int ncl = tid >> 7, l = (tid >> 1) & 63, eh = tid & 1;
    const int nl = ncl * 16 + (l & 15);
    const int klb = (l >> 4) * 8 + eh * 4;
    ushort4 o;
    {
      float v0 = tbuf[(klb + 0) * 33 + nl], v1 = tbuf[(klb + 1) * 33 + nl];
      float v2 = tbuf[(klb + 2) * 33 + nl], v3 = tbuf[(klb + 3) * 33 + nl];
      unsigned short h0 = f2bf(v0), h1 = f2bf(v1), h2 = f2bf(v2), h3 = f2bf(v3);
      if (z == 4) {
        h0 = f2bf(v0 - bf2f(h0)); h1 = f2bf(v1 - bf2f(h1));
        h2 = f2bf(v2 - bf2f(h2)); h3 = f2bf(v3 - bf2f(h3));
      }
      o.x = h0; o.y = h1; o.z = h2; o.w = h3;
    }
    size_t flat = (((size_t)((n0 >> 4) + ncl) * 16 + (k0 >> 5)) * 64 + l) * 8 + eh * 4;
    *(ushort4*)(dst + flat) = o;
  } else if (bid < 2344) {
    const int idx = bid - 2304;
    const int gx = idx % 5, h = idx / 5;
    const int g = gx * 256 + tid;
    if (g < 1040)
      Pkt[(size_t)h * 1040 + g] = (g < NUMREL) ? Pk[(size_t)g * Hh + h] : 0.f;
  } else {
    const int idx = bid - 2344;
    const int gx = idx & 15, h = idx >> 4;
    const int g0 = gx * 64;
#pragma unroll
    for (int u = 0; u < 20; ++u) {
      int i2 = u * 256 + tid, r = i2 >> 6, c = i2 & 63;
      int g = g0 + r;
      tbuf[r * 64 + c] = (g < NUMREL) ? Pv[(size_t)g * 512 + h * 64 + c] : 0.f;
    }
    __syncthreads();
#pragma unroll
    for (int av = 0; av < 2; ++av)
#pragma unroll
      for (int gtl = 0; gtl < 2; ++gtl) {
        int gt = (g0 >> 5) + gtl;
#pragma unroll
        for (int dt = 0; dt < 4; ++dt) {
          size_t base = ((((size_t)av * Hh + h) * 4 + dt) * 32 + gt) * 512;
          int i2 = tid * 2;
          int l = i2 >> 3, e = i2 & 7;
          int gr = av * 16 + gtl * 32 + (l >> 4) * 8 + e;
          int dcol = dt * 16 + (l & 15);
          ushort2 o;
          o.x = f2bf(tbuf[gr * 64 + dcol]);
          o.y = f2bf(tbuf[(gr + 1) * 64 + dcol]);
          *(ushort2*)(PvF2 + base + i2) = o;
        }
      }
  }
}

// ---------------------------------------------------------------------------
// gemm_qkv: z-fused, frag-major, BK=64 (8 barriers, 24 MFMA/wave/step).
// LDS: 2 x 32 KB. Outputs Qb row-major, KF / VF frag-major.
// ---------------------------------------------------------------------------
__global__ __launch_bounds__(256, 2) void gemm_qkv(const unsigned short* __restrict__ XbF,
                                                   const unsigned short* __restrict__ WqF,
                                                   const unsigned short* __restrict__ WkF,
                                                   const unsigned short* __restrict__ WvF,
                                                   const float* __restrict__ bq,
                                                   const float* __restrict__ bk,
                                                   const float* __restrict__ bv,
                                                   unsigned short* __restrict__ Qb,
                                                   unsigned short* __restrict__ KF,
                                                   unsigned short* __restrict__ VF) {
  const int flat = blockIdx.x;
  const int xcd = flat & 7, g = flat >> 3;
  const int by = xcd * 8 + (g & 7), bx = g >> 3;
  const int bm = by * 64, bn = bx * 64;
  const int mc0 = bm >> 4, nc0 = bn >> 4;
  const int tid = threadIdx.x, w = tid >> 6, lane = tid & 63;
  const int lo = lane & 15, quad = lane >> 4;
  const int mh = (w >> 1) * 2, nh = (w & 1) * 2;

  __shared__ __align__(16) unsigned short stg[2][32 * 512];

  const unsigned short* srcArr = w == 0 ? XbF : w == 1 ? WqF : w == 2 ? WkF : WvF;
  const int rowbase = (w == 0) ? mc0 : nc0;

#define STAGE(buf, ks)                                                             \
  do {                                                                             \
    _Pragma("unroll") for (int t = 0; t < 8; ++t) {                                \
      gl_lds16(srcArr +                                                            \
                   (((size_t)(rowbase + (t >> 1)) * 16 + 2 * (ks) + (t & 1)) * 512) + \
                   lane * 8,                                                       \
               &stg[buf][(w * 8 + t) * 512]);                                      \
    }                                                                              \
  } while (0)

  f32x4 acc[3][2][2] = {};
  STAGE(0, 0);
  int cur = 0;
#pragma unroll
  for (int ks = 0; ks < 8; ++ks) {
    __syncthreads();
    if (ks < 7) STAGE(cur ^ 1, ks + 1);
#pragma unroll
    for (int kf = 0; kf < 2; ++kf) {
      bf16x8 af[2], bq_[2], bk_[2], bv_[2];
#pragma unroll
      for (int i = 0; i < 2; ++i)
        af[i] = *(const bf16x8*)(&stg[cur][((mh + i) * 2 + kf) * 512 + lane * 8]);
#pragma unroll
      for (int j = 0; j < 2; ++j) {
        bq_[j] = *(const bf16x8*)(&stg[cur][(8 + (nh + j) * 2 + kf) * 512 + lane * 8]);
        bk_[j] = *(const bf16x8*)(&stg[cur][(16 + (nh + j) * 2 + kf) * 512 + lane * 8]);
        bv_[j] = *(const bf16x8*)(&stg[cur][(24 + (nh + j) * 2 + kf) * 512 + lane * 8]);
      }
#pragma unroll
      for (int i = 0; i < 2; ++i)
#pragma unroll
        for (int j = 0; j < 2; ++j) {
          acc[0][i][j] = __builtin_amdgcn_mfma_f32_16x16x32_bf16(af[i], bq_[j], acc[0][i][j], 0, 0, 0);
          acc[1][i][j] = __builtin_amdgcn_mfma_f32_16x16x32_bf16(af[i], bk_[j], acc[1][i][j], 0, 0, 0);
          acc[2][i][j] = __builtin_amdgcn_mfma_f32_16x16x32_bf16(af[i], bv_[j], acc[2][i][j], 0, 0, 0);
        }
    }
    cur ^= 1;
  }
#undef STAGE

  const int mt = (w >> 1) * 32, nt = (w & 1) * 32;
#pragma unroll
  for (int z = 0; z < 3; ++z) {
    const float* bias = z == 0 ? bq : z == 1 ? bk : bv;
#pragma unroll
    for (int i = 0; i < 2; ++i)
#pragma unroll
      for (int j = 0; j < 2; ++j) {
        int col = bn + nt + j * 16 + lo;
        int h = col >> 6, d = col & 63;
        float bb = bias[col];
#pragma unroll
        for (int r = 0; r < 4; ++r) {
          int row = bm + mt + i * 16 + quad * 4 + r;
          int b = row >> 9, is = row & 511;
          int bh = b * Hh + h;
          unsigned short val = f2bf(acc[z][i][j][r] + bb);
          if (z == 0) {
            Qb[((size_t)bh * Nseq + is) * 64 + d] = val;
          } else if (z == 1) {
            int jt = is >> 4, kf2 = d >> 5, l = ((d >> 3) & 3) * 16 + (is & 15), e = d & 7;
            KF[(((size_t)bh * 32 + jt) * 2 + kf2) * 512 + l * 8 + e] = val;
          } else {
            int dt = d >> 4, ks = is >> 5, l = ((is >> 3) & 3) * 16 + (d & 15), e = is & 7;
            VF[(((size_t)bh * 4 + dt) * 16 + ks) * 512 + l * 8 + e] = val;
          }
        }
      }
  }
}

// ---------------------------------------------------------------------------
// attn_fused: tile-pair, m97-style block-wide double-buffer (8 KB granules,
// plain __syncthreads, no manual waitcnt). LDS 52.7 KB -> 3 blocks/CU.
// red arrays aliased into stg[1] (dead between phase1 and V-staging).
// ---------------------------------------------------------------------------
__global__ __launch_bounds__(256, 3) void attn_fused(
    const unsigned short* __restrict__ Qb,
    const unsigned short* __restrict__ KF,
    const unsigned short* __restrict__ VF,
    const float* __restrict__ Pkt,
    const unsigned short* __restrict__ PvF2,
    unsigned short* __restrict__ AwFh,
    unsigned short* __restrict__ AwFl) {
  const int flat = blockIdx.x;
  const int h = flat & 7;           // XCD-pinned
  const int grp = flat >> 3;        // [0,128)
  const int b = grp >> 4;
  const int p = grp & 15;
  const int itA = (p >> 1) * 4 + (p & 1);  // pairs {it, it+2}
  const int i0A = itA * 16;
  const int bh = b * Hh + h;
  const int tid = threadIdx.x, w = tid >> 6, lane = tid & 63;
  const int lo = lane & 15, quad = lane >> 4;

  __shared__ __align__(16) unsigned short stg[2][4096];    // 2 x 8 KB granules
  __shared__ __align__(16) unsigned short pstA[16 * STR];  // 17.25 KB
  __shared__ __align__(16) unsigned short pstB[16 * STR];
  __shared__ float pk_lds[560];

  const int TB = 464 - i0A;  // tile-B Pv/Pk base; tile-A = TB + 32

  // zero pstrips
  int4 z4; z4.x = z4.y = z4.z = z4.w = 0;
  for (int c = tid; c < 16 * STR / 8; c += 256) {
    ((int4*)pstA)[c] = z4;
    ((int4*)pstB)[c] = z4;
  }
  for (int c = tid; c < 140; c += 256)
    *(float4*)(pk_lds + c * 4) = *(const float4*)(Pkt + (size_t)h * 1040 + TB + c * 4);

  const unsigned short* qA = Qb + ((size_t)bh * Nseq + i0A + lo) * 64;
  const unsigned short* qB = Qb + ((size_t)bh * Nseq + i0A + 32 + lo) * 64;
  bf16x8 qa0 = *(const bf16x8*)(qA + quad * 8);
  bf16x8 qa1 = *(const bf16x8*)(qA + 32 + quad * 8);
  bf16x8 qb0 = *(const bf16x8*)(qB + quad * 8);
  bf16x8 qb1 = *(const bf16x8*)(qB + 32 + quad * 8);

  const unsigned short* KFb = KF + (size_t)bh * 64 * 512;
  const unsigned short* VFb = VF + ((size_t)bh * 4 + w) * 16 * 512;
  const int aP = (TB >> 4) & 1, gtB = TB >> 5;
  const unsigned short* PFb = PvF2 + ((((size_t)aP * Hh + h) * 4 + w) * 32 + gtB) * 512;

#define KSTAGE(g, buf)                                                     \
  do {                                                                     \
    _Pragma("unroll") for (int c = 0; c < 2; ++c)                          \
        gl_lds16(KFb + ((size_t)(w * 8 + (g)) * 2 + c) * 512 + lane * 8,   \
                 &stg[buf][(w * 2 + c) * 512]);                            \
  } while (0)
#define VSTAGE(g, buf)                                                     \
  do {                                                                     \
    _Pragma("unroll") for (int c = 0; c < 2; ++c)                          \
        gl_lds16(VFb + ((size_t)(2 * (g) + c)) * 512 + lane * 8,           \
                 &stg[buf][(w * 2 + c) * 512]);                            \
  } while (0)
#define PSTAGE(g, buf)                                                     \
  do {                                                                     \
    _Pragma("unroll") for (int c = 0; c < 2; ++c)                          \
        gl_lds16(PFb + ((size_t)(2 * (g) + c)) * 512 + lane * 8,           \
                 &stg[buf][(w * 2 + c) * 512]);                            \
  } while (0)

  KSTAGE(0, 0);
  __syncthreads();  // drains K g0 + zero/pk writes; Q frags retire on use

  // ---------------- Phase 1: scores, 8 K-granules (1 strip each) ---------
  float svA[8][4], svB[8][4];
  float mA[4] = {-1e30f, -1e30f, -1e30f, -1e30f};
  float mB[4] = {-1e30f, -1e30f, -1e30f, -1e30f};
#pragma unroll
  for (int g = 0; g < 8; ++g) {
    bf16x8 k0 = *(const bf16x8*)(&stg[g & 1][(w * 2 + 0) * 512 + lane * 8]);
    bf16x8 k1 = *(const bf16x8*)(&stg[g & 1][(w * 2 + 1) * 512 + lane * 8]);
    if (g < 7) KSTAGE(g + 1, (g + 1) & 1);
    f32x4 cA = {0.f, 0.f, 0.f, 0.f};
    f32x4 cB = {0.f, 0.f, 0.f, 0.f};
    cA = __builtin_amdgcn_mfma_f32_16x16x32_bf16(qa0, k0, cA, 0, 0, 0);
    cA = __builtin_amdgcn_mfma_f32_16x16x32_bf16(qa1, k1, cA, 0, 0, 0);
    cB = __builtin_amdgcn_mfma_f32_16x16x32_bf16(qb0, k0, cB, 0, 0, 0);
    cB = __builtin_amdgcn_mfma_f32_16x16x32_bf16(qb1, k1, cB, 0, 0, 0);
    int j = w * 128 + g * 16 + lo;
#pragma unroll
    for (int r = 0; r < 4; ++r) {
      int rl = quad * 4 + r;
      int idx = j - rl + 15;
      float vA = (cA[r] + pk_lds[idx + 32]) * 0.125f;
      float vB = (cB[r] + pk_lds[idx]) * 0.125f;
      svA[g][r] = vA; svB[g][r] = vB;
      mA[r] = fmaxf(mA[r], vA);
      mB[r] = fmaxf(mB[r], vB);
    }
    __syncthreads();
  }

  // ---------------- softmax x2 (red arrays aliased into stg[1]) ----------
  float* redm = (float*)&stg[1][0];    // [2][4][16]
  float* redl = (float*)&stg[1][256];  // [2][4][16]
#pragma unroll
  for (int m = 1; m <= 8; m <<= 1)
#pragma unroll
    for (int r = 0; r < 4; ++r) {
      mA[r] = fmaxf(mA[r], __shfl_xor(mA[r], m));
      mB[r] = fmaxf(mB[r], __shfl_xor(mB[r], m));
    }
  if (lo == 0)
#pragma unroll
    for (int r = 0; r < 4; ++r) {
      redm[(0 * 4 + w) * 16 + quad * 4 + r] = mA[r];
      redm[(1 * 4 + w) * 16 + quad * 4 + r] = mB[r];
    }
  __syncthreads();
  float mfA[4], mfB[4];
#pragma unroll
  for (int r = 0; r < 4; ++r) {
    int rl = quad * 4 + r;
    mfA[r] = fmaxf(fmaxf(redm[rl], redm[16 + rl]), fmaxf(redm[32 + rl], redm[48 + rl]));
    mfB[r] = fmaxf(fmaxf(redm[64 + rl], redm[80 + rl]), fmaxf(redm[96 + rl], redm[112 + rl]));
  }
  float lA[4] = {0.f, 0.f, 0.f, 0.f}, lB[4] = {0.f, 0.f, 0.f, 0.f};
#pragma unroll
  for (int s = 0; s < 8; ++s)
#pragma unroll
    for (int r = 0; r < 4; ++r) {
      float eA = __expf(svA[s][r] - mfA[r]);
      float eB = __expf(svB[s][r] - mfB[r]);
      svA[s][r] = eA; svB[s][r] = eB;
      lA[r] += eA; lB[r] += eB;
    }
#pragma unroll
  for (int m = 1; m <= 8; m <<= 1)
#pragma unroll
    for (int r = 0; r < 4; ++r) {
      lA[r] += __shfl_xor(lA[r], m);
      lB[r] += __shfl_xor(lB[r], m);
    }
  if (lo == 0)
#pragma unroll
    for (int r = 0; r < 4; ++r) {
      redl[(0 * 4 + w) * 16 + quad * 4 + r] = lA[r];
      redl[(1 * 4 + w) * 16 + quad * 4 + r] = lB[r];
    }
  __syncthreads();
#pragma unroll
  for (int r = 0; r < 4; ++r) {
    int rl = quad * 4 + r;
    float liA = 1.f / (redl[rl] + redl[16 + rl] + redl[32 + rl] + redl[48 + rl]);
    float liB = 1.f / (redl[64 + rl] + redl[80 + rl] + redl[96 + rl] + redl[112 + rl]);
#pragma unroll
    for (int s = 0; s < 8; ++s) {
      int j = w * 128 + s * 16 + lo;
      pstA[rl * STR + 16 + j] = f2bf(svA[s][r] * liA);
      pstB[rl * STR + 16 + j] = f2bf(svB[s][r] * liB);
    }
  }
  VSTAGE(0, 0);       // stg[0] dead (last K read was g6); red lives in stg[1]
  __syncthreads();    // drains pstrip writes + V g0; red fully consumed

  // ---------------- Phase 2: P@V, 8 V-granules -----------------
  f32x4 oA = {0.f, 0.f, 0.f, 0.f};
  f32x4 oB = {0.f, 0.f, 0.f, 0.f};
#pragma unroll
  for (int g = 0; g < 8; ++g) {
    bf16x8 v0 = *(const bf16x8*)(&stg[g & 1][(w * 2 + 0) * 512 + lane * 8]);
    bf16x8 v1 = *(const bf16x8*)(&stg[g & 1][(w * 2 + 1) * 512 + lane * 8]);
    if (g < 7) VSTAGE(g + 1, (g + 1) & 1);
    else PSTAGE(0, 0);
#pragma unroll
    for (int c = 0; c < 2; ++c) {
      int ks = 2 * g + c;
      bf16x8 vv = c ? v1 : v0;
      bf16x8 pA = *(const bf16x8*)(&pstA[lo * STR + 16 + ks * 32 + quad * 8]);
      bf16x8 pB = *(const bf16x8*)(&pstB[lo * STR + 16 + ks * 32 + quad * 8]);
      oA = __builtin_amdgcn_mfma_f32_16x16x32_bf16(pA, vv, oA, 0, 0, 0);
      oB = __builtin_amdgcn_mfma_f32_16x16x32_bf16(pB, vv, oB, 0, 0, 0);
    }
    __syncthreads();
  }

  // ---------------- Phase 2b: P'@Pv, 9 Pv-granules (18 chunks) ----------
#pragma unroll
  for (int g = 0; g < 9; ++g) {
    bf16x8 p0 = *(const bf16x8*)(&stg[g & 1][(w * 2 + 0) * 512 + lane * 8]);
    bf16x8 p1 = *(const bf16x8*)(&stg[g & 1][(w * 2 + 1) * 512 + lane * 8]);
    if (g < 8) PSTAGE(g + 1, (g + 1) & 1);
#pragma unroll
    for (int c = 0; c < 2; ++c) {
      int cg = 2 * g + c;
      bf16x8 pvf = c ? p1 : p0;
      if (cg < 17) {  // tile B: ks = cg
        union { bf16x8 v; unsigned short s8[8]; } pa;
        if (cg == 16 && quad >= 2) {
#pragma unroll
          for (int e = 0; e < 8; ++e) pa.s8[e] = 0;
        } else {
          int base = lo * STR + cg * 32 + quad * 8 + lo + 1;
#pragma unroll
          for (int e = 0; e < 8; ++e) pa.s8[e] = pstB[base + e];
        }
        oB = __builtin_amdgcn_mfma_f32_16x16x32_bf16(pa.v, pvf, oB, 0, 0, 0);
      }
      if (cg >= 1) {  // tile A: ks = cg-1
        int ksA = cg - 1;
        union { bf16x8 v; unsigned short s8[8]; } pa;
        if (ksA == 16 && quad >= 2) {
#pragma unroll
          for (int e = 0; e < 8; ++e) pa.s8[e] = 0;
        } else {
          int base = lo * STR + ksA * 32 + quad * 8 + lo + 1;
#pragma unroll
          for (int e = 0; e < 8; ++e) pa.s8[e] = pstA[base + e];
        }
        oA = __builtin_amdgcn_mfma_f32_16x16x32_bf16(pa.v, pvf, oA, 0, 0, 0);
      }
    }
    __syncthreads();
  }

  // epilogue x2: A-frag-major AwF hi/lo
  const int kf = h * 2 + (w >> 1);
  const int lhi = ((w & 1) * 2 + (lo >> 3)) * 16;
#pragma unroll
  for (int t = 0; t < 2; ++t) {
    f32x4 o = t ? oB : oA;
    int mc = b * 32 + itA + t * 2;
#pragma unroll
    for (int r = 0; r < 4; ++r) {
      float ov = o[r];
      unsigned short hi = f2bf(ov);
      unsigned short lov = f2bf(ov - bf2f(hi));
      size_t fl = (((size_t)mc * 16 + kf) * 64 + lhi + quad * 4 + r) * 8 + (lo & 7);
      AwFh[fl] = hi;
      AwFl[fl] = lov;
    }
  }
#undef KSTAGE
#undef VSTAGE
#undef PSTAGE
}

// ---------------------------------------------------------------------------
// gemm_final: split-bf16 3-term, BK=64 (8 barriers, 24 MFMA/wave/step).
// ---------------------------------------------------------------------------
__global__ __launch_bounds__(256, 2) void gemm_final(const unsigned short* __restrict__ AhF,
                                                     const unsigned short* __restrict__ AlF,
                                                     const unsigned short* __restrict__ BhF,
                                                     const unsigned short* __restrict__ BlF,
                                                     const float* __restrict__ bo,
                                                     float* __restrict__ out) {
  const int flat = blockIdx.x;
  const int xcd = flat & 7, g = flat >> 3;
  const int by = xcd * 8 + (g & 7), bx = g >> 3;
  const int bm = by * 64, bn = bx * 64;
  const int mc0 = bm >> 4, nc0 = bn >> 4;
  const int tid = threadIdx.x, w = tid >> 6, lane = tid & 63;
  const int lo = lane & 15, quad = lane >> 4;
  const int mh = (w >> 1) * 2, nh = (w & 1) * 2;

  __shared__ __align__(16) unsigned short stg[2][32 * 512];

  const unsigned short* srcArr = w == 0 ? AhF : w == 1 ? AlF : w == 2 ? BhF : BlF;
  const int rowbase = (w < 2) ? mc0 : nc0;

#define STAGE2(buf, ks)                                                            \
  do {                                                                             \
    _Pragma("unroll") for (int t = 0; t < 8; ++t) {                                \
      gl_lds16(srcArr +                                                            \
                   (((size_t)(rowbase + (t >> 1)) * 16 + 2 * (ks) + (t & 1)) * 512) + \
                   lane * 8,                                                       \
               &stg[buf][(w * 8 + t) * 512]);                                      \
    }                                                                              \
  } while (0)

  f32x4 acc[2][2] = {};
  STAGE2(0, 0);
  int cur = 0;
#pragma unroll
  for (int ks = 0; ks < 8; ++ks) {
    __syncthreads();
    if (ks < 7) STAGE2(cur ^ 1, ks + 1);
#pragma unroll
    for (int kf = 0; kf < 2; ++kf) {
      bf16x8 ah[2], al[2], bh[2], bl[2];
#pragma unroll
      for (int i = 0; i < 2; ++i) {
        ah[i] = *(const bf16x8*)(&stg[cur][((mh + i) * 2 + kf) * 512 + lane * 8]);
        al[i] = *(const bf16x8*)(&stg[cur][(8 + (mh + i) * 2 + kf) * 512 + lane * 8]);
      }
#pragma unroll
      for (int j = 0; j < 2; ++j) {
        bh[j] = *(const bf16x8*)(&stg[cur][(16 + (nh + j) * 2 + kf) * 512 + lane * 8]);
        bl[j] = *(const bf16x8*)(&stg[cur][(24 + (nh + j) * 2 + kf) * 512 + lane * 8]);
      }
#pragma unroll
      for (int i = 0; i < 2; ++i)
#pragma unroll
        for (int j = 0; j < 2; ++j) {
          acc[i][j] = __builtin_amdgcn_mfma_f32_16x16x32_bf16(ah[i], bh[j], acc[i][j], 0, 0, 0);
          acc[i][j] = __builtin_amdgcn_mfma_f32_16x16x32_bf16(ah[i], bl[j], acc[i][j], 0, 0, 0);
          acc[i][j] = __builtin_amdgcn_mfma_f32_16x16x32_bf16(al[i], bh[j], acc[i][j], 0, 0, 0);
        }
    }
    cur ^= 1;
  }
#undef STAGE2

  const int mt = (w >> 1) * 32, nt = (w & 1) * 32;
#pragma unroll
  for (int i = 0; i < 2; ++i)
#pragma unroll
    for (int j = 0; j < 2; ++j) {
      int col = bn + nt + j * 16 + lo;
      float bb = bo[col];
#pragma unroll
      for (int r = 0; r < 4; ++r) {
        int row = bm + mt + i * 16 + quad * 4 + r;
        out[(size_t)row * DM + col] = acc[i][j][r] + bb;
      }
    }
}

// ---------------------------------------------------------------------------
extern "C" void kernel_launch(void* const* d_in, const int* in_sizes, int n_in,
                              void* d_out, int out_size, void* d_ws, size_t ws_size,
                              hipStream_t stream) {
  const float* X  = (const float*)d_in[0];
  const float* Wq = (const float*)d_in[1];
  const float* bq = (const float*)d_in[2];
  const float* Wk = (const float*)d_in[3];
  const float* bk = (const float*)d_in[4];
  const float* Wv = (const float*)d_in[5];
  const float* bv = (const float*)d_in[6];
  const float* Wo = (const float*)d_in[7];
  const float* bo = (const float*)d_in[8];
  const float* Pk = (const float*)d_in[9];
  const float* Pv = (const float*)d_in[10];
  float* out = (float*)d_out;

  char* p = (char*)d_ws;
  const size_t szX    = (size_t)Bc * Nseq * DM * 2;        // 4 MB
  const size_t szW    = (size_t)DM * DM * 2;               // 512 KB
  const size_t szPkt  = (size_t)Hh * 1040 * 4;
  const size_t szPvF2 = (size_t)2 * Hh * 4 * 32 * 512 * 2; // 2 MB
  const size_t szQKV  = (size_t)Bc * Hh * Nseq * 64 * 2;   // 4 MB
  unsigned short* XbF  = (unsigned short*)p; p += szX;
  unsigned short* WqF  = (unsigned short*)p; p += szW;
  unsigned short* WkF  = (unsigned short*)p; p += szW;
  unsigned short* WvF  = (unsigned short*)p; p += szW;
  unsigned short* WoFh = (unsigned short*)p; p += szW;
  unsigned short* WoFl = (unsigned short*)p; p += szW;
  float*          Pkt  = (float*)p;          p += (szPkt + 255) & ~(size_t)255;
  unsigned short* PvF2 = (unsigned short*)p; p += szPvF2;
  unsigned short* Qb   = (unsigned short*)p; p += szQKV;
  unsigned short* KF   = (unsigned short*)p; p += szQKV;
  unsigned short* VF   = (unsigned short*)p; p += szQKV;
  unsigned short* AwFh = (unsigned short*)p; p += szX;
  unsigned short* AwFl = (unsigned short*)p; p += szX;

  dim3 blk(256);
  prep_all<<<dim3(2472), blk, 0, stream>>>(X, Wq, Wk, Wv, Wo, Pk, Pv,
                                           XbF, WqF, WkF, WvF, WoFh, WoFl, Pkt, PvF2);
  gemm_qkv<<<dim3(512), blk, 0, stream>>>(XbF, WqF, WkF, WvF, bq, bk, bv, Qb, KF, VF);
  attn_fused<<<dim3(1024), blk, 0, stream>>>(Qb, KF, VF, Pkt, PvF2, AwFh, AwFl);
  gemm_final<<<dim3(512), blk, 0, stream>>>(AwFh, AwFl, WoFh, WoFl, bo, out);
}

// Round 12
// 143.297 us; speedup vs baseline: 1.3749x; 1.0269x over previous
//
#include <hip/hip_runtime.h>
#include <math.h>

#define Bc 8
#define Nseq 512
#define DM 512
#define Hh 8
#define NUMREL 1023
#define ZOFF 511   // NUMREL/2
#define STR 552    // pstrip row stride (shorts)

typedef _Float16 half8 __attribute__((ext_vector_type(8)));
typedef float f32x4 __attribute__((ext_vector_type(4)));

__device__ __forceinline__ unsigned short f2h(float f) {
  _Float16 h = (_Float16)f;  // v_cvt_f16_f32, RNE
  return __builtin_bit_cast(unsigned short, h);
}

typedef __attribute__((address_space(3))) unsigned int as3_uint;
typedef __attribute__((address_space(1))) const unsigned int as1_uint;
__device__ __forceinline__ void gl_lds16(const void* g, void* l) {
  __builtin_amdgcn_global_load_lds((as1_uint*)g, (as3_uint*)l, 16, 0, 0);
}

// ---------------------------------------------------------------------------
// prep_all: bid [0,1024) X->XbF (A-frag-major fp16); [1024,2048) W->WqF/WkF/
// WvF/WoF (B-frag-major fp16); [2048,2088) Pk->Pkt fp32; [2088,2216) Pv->PvF2.
// ---------------------------------------------------------------------------
__global__ __launch_bounds__(256) void prep_all(
    const float* __restrict__ X, const float* __restrict__ Wq,
    const float* __restrict__ Wk, const float* __restrict__ Wv,
    const float* __restrict__ Wo, const float* __restrict__ Pk,
    const float* __restrict__ Pv,
    unsigned short* __restrict__ XbF, unsigned short* __restrict__ WqF,
    unsigned short* __restrict__ WkF, unsigned short* __restrict__ WvF,
    unsigned short* __restrict__ WoF,
    float* __restrict__ Pkt, unsigned short* __restrict__ PvF2) {
  __shared__ float tbuf[5120];
  const int bid = blockIdx.x;
  const int tid = threadIdx.x;

  if (bid < 1024) {
    const int w = tid >> 6, lane = tid & 63;
    const int r = bid * 4 + w;
    const float* src = X + (size_t)r * DM + lane * 8;
    float4 a = *(const float4*)src;
    float4 b = *(const float4*)(src + 4);
    ushort4 o0, o1;
    o0.x = f2h(a.x); o0.y = f2h(a.y); o0.z = f2h(a.z); o0.w = f2h(a.w);
    o1.x = f2h(b.x); o1.y = f2h(b.y); o1.z = f2h(b.z); o1.w = f2h(b.w);
    const int mc = r >> 4, kf = lane >> 2, l = (lane & 3) * 16 + (r & 15);
    size_t flat = (((size_t)mc * 16 + kf) * 64 + l) * 8;
    *(ushort4*)(XbF + flat) = o0;
    *(ushort4*)(XbF + flat + 4) = o1;
  } else if (bid < 2048) {
    const int idx = bid - 1024;
    const int z = idx >> 8, r256 = idx & 255;
    const int bx = r256 & 15, by = r256 >> 4;
    const float* src = z == 0 ? Wq : z == 1 ? Wk : z == 2 ? Wv : Wo;
    unsigned short* dst = z == 0 ? WqF : z == 1 ? WkF : z == 2 ? WvF : WoF;
    const int k0 = by * 32, n0 = bx * 32;
#pragma unroll
    for (int u = 0; u < 4; ++u) {
      int i2 = u * 256 + tid, r = i2 >> 5, c = i2 & 31;
      tbuf[r * 33 + c] = src[(size_t)(k0 + r) * DM + n0 + c];
    }
    __syncthreads();
    const int ncl = tid >> 7, l = (tid >> 1) & 63, eh = tid & 1;
    const int nl = ncl * 16 + (l & 15);
    const int klb = (l >> 4) * 8 + eh * 4;
    ushort4 o;
    o.x = f2h(tbuf[(klb + 0) * 33 + nl]);
    o.y = f2h(tbuf[(klb + 1) * 33 + nl]);
    o.z = f2h(tbuf[(klb + 2) * 33 + nl]);
    o.w = f2h(tbuf[(klb + 3) * 33 + nl]);
    size_t flat = (((size_t)((n0 >> 4) + ncl) * 16 + (k0 >> 5)) * 64 + l) * 8 + eh * 4;
    *(ushort4*)(dst + flat) = o;
  } else if (bid < 2088) {
    const int idx = bid - 2048;
    const int gx = idx % 5, h = idx / 5;
    const int g = gx * 256 + tid;
    if (g < 1040)
      Pkt[(size_t)h * 1040 + g] = (g < NUMREL) ? Pk[(size_t)g * Hh + h] : 0.f;
  } else {
    const int idx = bid - 2088;
    const int gx = idx & 15, h = idx >> 4;
    const int g0 = gx * 64;
#pragma unroll
    for (int u = 0; u < 20; ++u) {
      int i2 = u * 256 + tid, r = i2 >> 6, c = i2 & 63;
      int g = g0 + r;
      tbuf[r * 64 + c] = (g < NUMREL) ? Pv[(size_t)g * 512 + h * 64 + c] : 0.f;
    }
    __syncthreads();
#pragma unroll
    for (int av = 0; av < 2; ++av)
#pragma unroll
      for (int gtl = 0; gtl < 2; ++gtl) {
        int gt = (g0 >> 5) + gtl;
#pragma unroll
        for (int dt = 0; dt < 4; ++dt) {
          size_t base = ((((size_t)av * Hh + h) * 4 + dt) * 32 + gt) * 512;
          int i2 = tid * 2;
          int l = i2 >> 3, e = i2 & 7;
          int gr = av * 16 + gtl * 32 + (l >> 4) * 8 + e;
          int dcol = dt * 16 + (l & 15);
          ushort2 o;
          o.x = f2h(tbuf[gr * 64 + dcol]);
          o.y = f2h(tbuf[(gr + 1) * 64 + dcol]);
          *(ushort2*)(PvF2 + base + i2) = o;
        }
      }
  }
}

// ---------------------------------------------------------------------------
// gemm_qkv: z-fused fp16 MFMA, frag-major, BK=64 staged (unchanged structure).
// ---------------------------------------------------------------------------
__global__ __launch_bounds__(256, 2) void gemm_qkv(const unsigned short* __restrict__ XbF,
                                                   const unsigned short* __restrict__ WqF,
                                                   const unsigned short* __restrict__ WkF,
                                                   const unsigned short* __restrict__ WvF,
                                                   const float* __restrict__ bq,
                                                   const float* __restrict__ bk,
                                                   const float* __restrict__ bv,
                                                   unsigned short* __restrict__ Qb,
                                                   unsigned short* __restrict__ KF,
                                                   unsigned short* __restrict__ VF) {
  const int flat = blockIdx.x;
  const int xcd = flat & 7, g = flat >> 3;
  const int by = xcd * 8 + (g & 7), bx = g >> 3;
  const int bm = by * 64, bn = bx * 64;
  const int mc0 = bm >> 4, nc0 = bn >> 4;
  const int tid = threadIdx.x, w = tid >> 6, lane = tid & 63;
  const int lo = lane & 15, quad = lane >> 4;
  const int mh = (w >> 1) * 2, nh = (w & 1) * 2;

  __shared__ __align__(16) unsigned short stg[2][32 * 512];

  const unsigned short* srcArr = w == 0 ? XbF : w == 1 ? WqF : w == 2 ? WkF : WvF;
  const int rowbase = (w == 0) ? mc0 : nc0;

#define STAGE(buf, ks)                                                             \
  do {                                                                             \
    _Pragma("unroll") for (int t = 0; t < 8; ++t) {                                \
      gl_lds16(srcArr +                                                            \
                   (((size_t)(rowbase + (t >> 1)) * 16 + 2 * (ks) + (t & 1)) * 512) + \
                   lane * 8,                                                       \
               &stg[buf][(w * 8 + t) * 512]);                                      \
    }                                                                              \
  } while (0)

  f32x4 acc[3][2][2] = {};
  STAGE(0, 0);
  int cur = 0;
#pragma unroll
  for (int ks = 0; ks < 8; ++ks) {
    __syncthreads();
    if (ks < 7) STAGE(cur ^ 1, ks + 1);
#pragma unroll
    for (int kf = 0; kf < 2; ++kf) {
      half8 af[2], bq_[2], bk_[2], bv_[2];
#pragma unroll
      for (int i = 0; i < 2; ++i)
        af[i] = *(const half8*)(&stg[cur][((mh + i) * 2 + kf) * 512 + lane * 8]);
#pragma unroll
      for (int j = 0; j < 2; ++j) {
        bq_[j] = *(const half8*)(&stg[cur][(8 + (nh + j) * 2 + kf) * 512 + lane * 8]);
        bk_[j] = *(const half8*)(&stg[cur][(16 + (nh + j) * 2 + kf) * 512 + lane * 8]);
        bv_[j] = *(const half8*)(&stg[cur][(24 + (nh + j) * 2 + kf) * 512 + lane * 8]);
      }
#pragma unroll
      for (int i = 0; i < 2; ++i)
#pragma unroll
        for (int j = 0; j < 2; ++j) {
          acc[0][i][j] = __builtin_amdgcn_mfma_f32_16x16x32_f16(af[i], bq_[j], acc[0][i][j], 0, 0, 0);
          acc[1][i][j] = __builtin_amdgcn_mfma_f32_16x16x32_f16(af[i], bk_[j], acc[1][i][j], 0, 0, 0);
          acc[2][i][j] = __builtin_amdgcn_mfma_f32_16x16x32_f16(af[i], bv_[j], acc[2][i][j], 0, 0, 0);
        }
    }
    cur ^= 1;
  }
#undef STAGE

  const int mt = (w >> 1) * 32, nt = (w & 1) * 32;
#pragma unroll
  for (int z = 0; z < 3; ++z) {
    const float* bias = z == 0 ? bq : z == 1 ? bk : bv;
#pragma unroll
    for (int i = 0; i < 2; ++i)
#pragma unroll
      for (int j = 0; j < 2; ++j) {
        int col = bn + nt + j * 16 + lo;
        int h = col >> 6, d = col & 63;
        float bb = bias[col];
#pragma unroll
        for (int r = 0; r < 4; ++r) {
          int row = bm + mt + i * 16 + quad * 4 + r;
          int b = row >> 9, is = row & 511;
          int bh = b * Hh + h;
          unsigned short val = f2h(acc[z][i][j][r] + bb);
          if (z == 0) {
            Qb[((size_t)bh * Nseq + is) * 64 + d] = val;
          } else if (z == 1) {
            int jt = is >> 4, kf2 = d >> 5, l = ((d >> 3) & 3) * 16 + (is & 15), e = d & 7;
            KF[(((size_t)bh * 32 + jt) * 2 + kf2) * 512 + l * 8 + e] = val;
          } else {
            int dt = d >> 4, ks = is >> 5, l = ((is >> 3) & 3) * 16 + (d & 15), e = is & 7;
            VF[(((size_t)bh * 4 + dt) * 16 + ks) * 512 + l * 8 + e] = val;
          }
        }
      }
  }
}

// ---------------------------------------------------------------------------
// attn_fused: tile-pair, block-wide double-buffer, fp16. Deferred 1/l
// normalization (applied in epilogue); split V/Pv accumulators; single AwF out.
// ---------------------------------------------------------------------------
__global__ __launch_bounds__(256, 3) void attn_fused(
    const unsigned short* __restrict__ Qb,
    const unsigned short* __restrict__ KF,
    const unsigned short* __restrict__ VF,
    const float* __restrict__ Pkt,
    const unsigned short* __restrict__ PvF2,
    unsigned short* __restrict__ AwF) {
  const int flat = blockIdx.x;
  const int h = flat & 7;
  const int grp = flat >> 3;
  const int b = grp >> 4;
  const int p = grp & 15;
  const int itA = (p >> 1) * 4 + (p & 1);  // pairs {it, it+2}
  const int i0A = itA * 16;
  const int bh = b * Hh + h;
  const int tid = threadIdx.x, w = tid >> 6, lane = tid & 63;
  const int lo = lane & 15, quad = lane >> 4;

  __shared__ __align__(16) unsigned short stg[2][4096];
  __shared__ __align__(16) unsigned short pstA[16 * STR];
  __shared__ __align__(16) unsigned short pstB[16 * STR];
  __shared__ float pk_lds[560];

  const int TB = 464 - i0A;

  int4 z4; z4.x = z4.y = z4.z = z4.w = 0;
  for (int c = tid; c < 16 * STR / 8; c += 256) {
    ((int4*)pstA)[c] = z4;
    ((int4*)pstB)[c] = z4;
  }
  for (int c = tid; c < 140; c += 256)
    *(float4*)(pk_lds + c * 4) = *(const float4*)(Pkt + (size_t)h * 1040 + TB + c * 4);

  const unsigned short* qA = Qb + ((size_t)bh * Nseq + i0A + lo) * 64;
  const unsigned short* qB = Qb + ((size_t)bh * Nseq + i0A + 32 + lo) * 64;
  half8 qa0 = *(const half8*)(qA + quad * 8);
  half8 qa1 = *(const half8*)(qA + 32 + quad * 8);
  half8 qb0 = *(const half8*)(qB + quad * 8);
  half8 qb1 = *(const half8*)(qB + 32 + quad * 8);

  const unsigned short* KFb = KF + (size_t)bh * 64 * 512;
  const unsigned short* VFb = VF + ((size_t)bh * 4 + w) * 16 * 512;
  const int aP = (TB >> 4) & 1, gtB = TB >> 5;
  const unsigned short* PFb = PvF2 + ((((size_t)aP * Hh + h) * 4 + w) * 32 + gtB) * 512;

#define KSTAGE(g, buf)                                                     \
  do {                                                                     \
    _Pragma("unroll") for (int c = 0; c < 2; ++c)                          \
        gl_lds16(KFb + ((size_t)(w * 8 + (g)) * 2 + c) * 512 + lane * 8,   \
                 &stg[buf][(w * 2 + c) * 512]);                            \
  } while (0)
#define VSTAGE(g, buf)                                                     \
  do {                                                                     \
    _Pragma("unroll") for (int c = 0; c < 2; ++c)                          \
        gl_lds16(VFb + ((size_t)(2 * (g) + c)) * 512 + lane * 8,           \
                 &stg[buf][(w * 2 + c) * 512]);                            \
  } while (0)
#define PSTAGE(g, buf)                                                     \
  do {                                                                     \
    _Pragma("unroll") for (int c = 0; c < 2; ++c)                          \
        gl_lds16(PFb + ((size_t)(2 * (g) + c)) * 512 + lane * 8,           \
                 &stg[buf][(w * 2 + c) * 512]);                            \
  } while (0)

  KSTAGE(0, 0);
  __syncthreads();

  // ---------------- Phase 1: scores ----------------
  float svA[8][4], svB[8][4];
  float mA[4] = {-1e30f, -1e30f, -1e30f, -1e30f};
  float mB[4] = {-1e30f, -1e30f, -1e30f, -1e30f};
#pragma unroll
  for (int g = 0; g < 8; ++g) {
    half8 k0 = *(const half8*)(&stg[g & 1][(w * 2 + 0) * 512 + lane * 8]);
    half8 k1 = *(const half8*)(&stg[g & 1][(w * 2 + 1) * 512 + lane * 8]);
    if (g < 7) KSTAGE(g + 1, (g + 1) & 1);
    f32x4 cA = {0.f, 0.f, 0.f, 0.f};
    f32x4 cB = {0.f, 0.f, 0.f, 0.f};
    cA = __builtin_amdgcn_mfma_f32_16x16x32_f16(qa0, k0, cA, 0, 0, 0);
    cA = __builtin_amdgcn_mfma_f32_16x16x32_f16(qa1, k1, cA, 0, 0, 0);
    cB = __builtin_amdgcn_mfma_f32_16x16x32_f16(qb0, k0, cB, 0, 0, 0);
    cB = __builtin_amdgcn_mfma_f32_16x16x32_f16(qb1, k1, cB, 0, 0, 0);
    int j = w * 128 + g * 16 + lo;
#pragma unroll
    for (int r = 0; r < 4; ++r) {
      int rl = quad * 4 + r;
      int idx = j - rl + 15;
      float vA = (cA[r] + pk_lds[idx + 32]) * 0.125f;
      float vB = (cB[r] + pk_lds[idx]) * 0.125f;
      svA[g][r] = vA; svB[g][r] = vB;
      mA[r] = fmaxf(mA[r], vA);
      mB[r] = fmaxf(mB[r], vB);
    }
    __syncthreads();
  }

  // ---------------- softmax x2 (red aliased into stg[1]) ----------------
  float* redm = (float*)&stg[1][0];
  float* redl = (float*)&stg[1][256];
#pragma unroll
  for (int m = 1; m <= 8; m <<= 1)
#pragma unroll
    for (int r = 0; r < 4; ++r) {
      mA[r] = fmaxf(mA[r], __shfl_xor(mA[r], m));
      mB[r] = fmaxf(mB[r], __shfl_xor(mB[r], m));
    }
  if (lo == 0)
#pragma unroll
    for (int r = 0; r < 4; ++r) {
      redm[(0 * 4 + w) * 16 + quad * 4 + r] = mA[r];
      redm[(1 * 4 + w) * 16 + quad * 4 + r] = mB[r];
    }
  __syncthreads();
  float mfA[4], mfB[4];
#pragma unroll
  for (int r = 0; r < 4; ++r) {
    int rl = quad * 4 + r;
    mfA[r] = fmaxf(fmaxf(redm[rl], redm[16 + rl]), fmaxf(redm[32 + rl], redm[48 + rl]));
    mfB[r] = fmaxf(fmaxf(redm[64 + rl], redm[80 + rl]), fmaxf(redm[96 + rl], redm[112 + rl]));
  }
  float lA[4] = {0.f, 0.f, 0.f, 0.f}, lB[4] = {0.f, 0.f, 0.f, 0.f};
#pragma unroll
  for (int s = 0; s < 8; ++s)
#pragma unroll
    for (int r = 0; r < 4; ++r) {
      float eA = __expf(svA[s][r] - mfA[r]);
      float eB = __expf(svB[s][r] - mfB[r]);
      svA[s][r] = eA; svB[s][r] = eB;
      lA[r] += eA; lB[r] += eB;
    }
#pragma unroll
  for (int m = 1; m <= 8; m <<= 1)
#pragma unroll
    for (int r = 0; r < 4; ++r) {
      lA[r] += __shfl_xor(lA[r], m);
      lB[r] += __shfl_xor(lB[r], m);
    }
  if (lo == 0)
#pragma unroll
    for (int r = 0; r < 4; ++r) {
      redl[(0 * 4 + w) * 16 + quad * 4 + r] = lA[r];
      redl[(1 * 4 + w) * 16 + quad * 4 + r] = lB[r];
    }
  __syncthreads();
  // unnormalized exp -> pstrips (1/l deferred to epilogue)
  float liA[4], liB[4];
#pragma unroll
  for (int r = 0; r < 4; ++r) {
    int rl = quad * 4 + r;
    liA[r] = 1.f / (redl[rl] + redl[16 + rl] + redl[32 + rl] + redl[48 + rl]);
    liB[r] = 1.f / (redl[64 + rl] + redl[80 + rl] + redl[96 + rl] + redl[112 + rl]);
#pragma unroll
    for (int s = 0; s < 8; ++s) {
      int j = w * 128 + s * 16 + lo;
      pstA[rl * STR + 16 + j] = f2h(svA[s][r]);
      pstB[rl * STR + 16 + j] = f2h(svB[s][r]);
    }
  }
  VSTAGE(0, 0);
  __syncthreads();

  // ---------------- Phase 2: P@V ----------------
  f32x4 oVA = {0.f, 0.f, 0.f, 0.f}, oVB = {0.f, 0.f, 0.f, 0.f};
#pragma unroll
  for (int g = 0; g < 8; ++g) {
    half8 v0 = *(const half8*)(&stg[g & 1][(w * 2 + 0) * 512 + lane * 8]);
    half8 v1 = *(const half8*)(&stg[g & 1][(w * 2 + 1) * 512 + lane * 8]);
    if (g < 7) VSTAGE(g + 1, (g + 1) & 1);
    else PSTAGE(0, 0);
#pragma unroll
    for (int c = 0; c < 2; ++c) {
      int ks = 2 * g + c;
      half8 vv = c ? v1 : v0;
      half8 pA = *(const half8*)(&pstA[lo * STR + 16 + ks * 32 + quad * 8]);
      half8 pB = *(const half8*)(&pstB[lo * STR + 16 + ks * 32 + quad * 8]);
      oVA = __builtin_amdgcn_mfma_f32_16x16x32_f16(pA, vv, oVA, 0, 0, 0);
      oVB = __builtin_amdgcn_mfma_f32_16x16x32_f16(pB, vv, oVB, 0, 0, 0);
    }
    __syncthreads();
  }

  // ---------------- Phase 2b: P'@Pv ----------------
  f32x4 oPA = {0.f, 0.f, 0.f, 0.f}, oPB = {0.f, 0.f, 0.f, 0.f};
#pragma unroll
  for (int g = 0; g < 9; ++g) {
    half8 p0 = *(const half8*)(&stg[g & 1][(w * 2 + 0) * 512 + lane * 8]);
    half8 p1 = *(const half8*)(&stg[g & 1][(w * 2 + 1) * 512 + lane * 8]);
    if (g < 8) PSTAGE(g + 1, (g + 1) & 1);
#pragma unroll
    for (int c = 0; c < 2; ++c) {
      int cg = 2 * g + c;
      half8 pvf = c ? p1 : p0;
      if (cg < 17) {
        union { half8 v; unsigned short s8[8]; } pa;
        if (cg == 16 && quad >= 2) {
#pragma unroll
          for (int e = 0; e < 8; ++e) pa.s8[e] = 0;
        } else {
          int base = lo * STR + cg * 32 + quad * 8 + lo + 1;
#pragma unroll
          for (int e = 0; e < 8; ++e) pa.s8[e] = pstB[base + e];
        }
        oPB = __builtin_amdgcn_mfma_f32_16x16x32_f16(pa.v, pvf, oPB, 0, 0, 0);
      }
      if (cg >= 1) {
        int ksA = cg - 1;
        union { half8 v; unsigned short s8[8]; } pa;
        if (ksA == 16 && quad >= 2) {
#pragma unroll
          for (int e = 0; e < 8; ++e) pa.s8[e] = 0;
        } else {
          int base = lo * STR + ksA * 32 + quad * 8 + lo + 1;
#pragma unroll
          for (int e = 0; e < 8; ++e) pa.s8[e] = pstA[base + e];
        }
        oPA = __builtin_amdgcn_mfma_f32_16x16x32_f16(pa.v, pvf, oPA, 0, 0, 0);
      }
    }
    __syncthreads();
  }

  // epilogue x2: single A-frag-major AwF, normalize here
  const int kf = h * 2 + (w >> 1);
  const int lhi = ((w & 1) * 2 + (lo >> 3)) * 16;
#pragma unroll
  for (int t = 0; t < 2; ++t) {
    int mc = b * 32 + itA + t * 2;
#pragma unroll
    for (int r = 0; r < 4; ++r) {
      float ov = t ? (oVB[r] + oPB[r]) * liB[r] : (oVA[r] + oPA[r]) * liA[r];
      size_t fl = (((size_t)mc * 16 + kf) * 64 + lhi + quad * 4 + r) * 8 + (lo & 7);
      AwF[fl] = f2h(ov);
    }
  }
#undef KSTAGE
#undef VSTAGE
#undef PSTAGE
}

// ---------------------------------------------------------------------------
// gemm_final: single-term fp16 MFMA, BK=64 staged. out = AwF @ WoF + bo.
// ---------------------------------------------------------------------------
__global__ __launch_bounds__(256, 2) void gemm_final(const unsigned short* __restrict__ AF,
                                                     const unsigned short* __restrict__ BF,
                                                     const float* __restrict__ bo,
                                                     float* __restrict__ out) {
  const int flat = blockIdx.x;
  const int xcd = flat & 7, g = flat >> 3;
  const int by = xcd * 8 + (g & 7), bx = g >> 3;
  const int bm = by * 64, bn = bx * 64;
  const int mc0 = bm >> 4, nc0 = bn >> 4;
  const int tid = threadIdx.x, w = tid >> 6, lane = tid & 63;
  const int lo = lane & 15, quad = lane >> 4;
  const int mh = (w >> 1) * 2, nh = (w & 1) * 2;

  __shared__ __align__(16) unsigned short stg[2][16 * 512];

  // waves 0,1 stage A (2 rows x 2 kf each); waves 2,3 stage B
  const unsigned short* srcArr = (w < 2) ? AF : BF;
  const int rowbase = ((w < 2) ? mc0 : nc0) + (w & 1) * 2;

#define STAGE2(buf, ks)                                                            \
  do {                                                                             \
    _Pragma("unroll") for (int t = 0; t < 4; ++t) {                                \
      gl_lds16(srcArr +                                                            \
                   (((size_t)(rowbase + (t >> 1)) * 16 + 2 * (ks) + (t & 1)) * 512) + \
                   lane * 8,                                                       \
               &stg[buf][(w * 4 + t) * 512]);                                      \
    }                                                                              \
  } while (0)

  f32x4 acc[2][2] = {};
  STAGE2(0, 0);
  int cur = 0;
#pragma unroll
  for (int ks = 0; ks < 8; ++ks) {
    __syncthreads();
    if (ks < 7) STAGE2(cur ^ 1, ks + 1);
#pragma unroll
    for (int kf = 0; kf < 2; ++kf) {
      half8 af[2], bf[2];
#pragma unroll
      for (int i = 0; i < 2; ++i)
        af[i] = *(const half8*)(&stg[cur][((mh + i) * 2 + kf) * 512 + lane * 8]);
#pragma unroll
      for (int j = 0; j < 2; ++j)
        bf[j] = *(const half8*)(&stg[cur][(8 + (nh + j) * 2 + kf) * 512 + lane * 8]);
#pragma unroll
      for (int i = 0; i < 2; ++i)
#pragma unroll
        for (int j = 0; j < 2; ++j)
          acc[i][j] = __builtin_amdgcn_mfma_f32_16x16x32_f16(af[i], bf[j], acc[i][j], 0, 0, 0);
    }
    cur ^= 1;
  }
#undef STAGE2

  const int mt = (w >> 1) * 32, nt = (w & 1) * 32;
#pragma unroll
  for (int i = 0; i < 2; ++i)
#pragma unroll
    for (int j = 0; j < 2; ++j) {
      int col = bn + nt + j * 16 + lo;
      float bb = bo[col];
#pragma unroll
      for (int r = 0; r < 4; ++r) {
        int row = bm + mt + i * 16 + quad * 4 + r;
        out[(size_t)row * DM + col] = acc[i][j][r] + bb;
      }
    }
}

// ---------------------------------------------------------------------------
extern "C" void kernel_launch(void* const* d_in, const int* in_sizes, int n_in,
                              void* d_out, int out_size, void* d_ws, size_t ws_size,
                              hipStream_t stream) {
  const float* X  = (const float*)d_in[0];
  const float* Wq = (const float*)d_in[1];
  const float* bq = (const float*)d_in[2];
  const float* Wk = (const float*)d_in[3];
  const float* bk = (const float*)d_in[4];
  const float* Wv = (const float*)d_in[5];
  const float* bv = (const float*)d_in[6];
  const float* Wo = (const float*)d_in[7];
  const float* bo = (const float*)d_in[8];
  const float* Pk = (const float*)d_in[9];
  const float* Pv = (const float*)d_in[10];
  float* out = (float*)d_out;

  char* p = (char*)d_ws;
  const size_t szX    = (size_t)Bc * Nseq * DM * 2;        // 4 MB
  const size_t szW    = (size_t)DM * DM * 2;               // 512 KB
  const size_t szPkt  = (size_t)Hh * 1040 * 4;
  const size_t szPvF2 = (size_t)2 * Hh * 4 * 32 * 512 * 2; // 2 MB
  const size_t szQKV  = (size_t)Bc * Hh * Nseq * 64 * 2;   // 4 MB
  unsigned short* XbF = (unsigned short*)p; p += szX;
  unsigned short* WqF = (unsigned short*)p; p += szW;
  unsigned short* WkF = (unsigned short*)p; p += szW;
  unsigned short* WvF = (unsigned short*)p; p += szW;
  unsigned short* WoF = (unsigned short*)p; p += szW;
  float*          Pkt = (float*)p;          p += (szPkt + 255) & ~(size_t)255;
  unsigned short* PvF2 = (unsigned short*)p; p += szPvF2;
  unsigned short* Qb  = (unsigned short*)p; p += szQKV;
  unsigned short* KF  = (unsigned short*)p; p += szQKV;
  unsigned short* VF  = (unsigned short*)p; p += szQKV;
  unsigned short* AwF = (unsigned short*)p; p += szX;

  dim3 blk(256);
  prep_all<<<dim3(2216), blk, 0, stream>>>(X, Wq, Wk, Wv, Wo, Pk, Pv,
                                           XbF, WqF, WkF, WvF, WoF, Pkt, PvF2);
  gemm_qkv<<<dim3(512), blk, 0, stream>>>(XbF, WqF, WkF, WvF, bq, bk, bv, Qb, KF, VF);
  attn_fused<<<dim3(1024), blk, 0, stream>>>(Qb, KF, VF, Pkt, PvF2, AwF);
  gemm_final<<<dim3(512), blk, 0, stream>>>(AwF, WoF, bo, out);
}